// Round 16
// baseline (324.649 us; speedup 1.0000x reference)
//
#include <hip/hip_runtime.h>
#include <math.h>

#define TD 1024      // model dim
#define NH 16        // heads
#define HDIM 64      // head dim
#define SEQ 2048     // seq len
#define NB 2         // batch
#define NROWS 4096   // NB*SEQ
#define FFD 4096     // ffn dim

// 1/sqrt(64) * log2(e): softmax computed in exp2 domain; folded into Q at QKV epilogue
#define QSCALE 0.18033688011112042f

typedef unsigned short u16;
typedef __attribute__((ext_vector_type(8))) short bf16x8;   // 8 bf16 = 4 VGPR
typedef __attribute__((ext_vector_type(4))) float f32x4;    // MFMA acc

__device__ __forceinline__ u16 f2bf(float f) {
    union { float f; unsigned u; } v; v.f = f;
    return (u16)((v.u + 0x7FFFu + ((v.u >> 16) & 1u)) >> 16);
}

// async global->LDS, 16B per lane. LDS dest must be wave-uniform base + lane*16.
__device__ __forceinline__ void async16(void* lds, const void* g) {
    __builtin_amdgcn_global_load_lds(
        (const __attribute__((address_space(1))) unsigned*)g,
        (__attribute__((address_space(3))) unsigned*)lds, 16, 0, 0);
}

// tanh-form GELU (max |err| vs exact erf-GELU ~3e-3; threshold headroom 4x)
__device__ __forceinline__ float gelu_f(float v) {
    float u = 0.7978845608028654f * (v + 0.044715f * v * v * v);
    float e = __expf(2.f * u);
    float th = 1.f - 2.f * __builtin_amdgcn_rcpf(e + 1.f);
    return 0.5f * v * (1.f + th);
}

// ---------------- LayerNorm -> bf16 out: one block per row of 1024 -------------
__global__ __launch_bounds__(256) void ln_bf16(const float* __restrict__ x,
                                               const float* __restrict__ g,
                                               const float* __restrict__ b,
                                               u16* __restrict__ out)
{
    int row = blockIdx.x;
    const float* xr = x + (size_t)row * TD;
    u16* outr = out + (size_t)row * TD;
    int t = threadIdx.x;
    float v[4];
    float s = 0.f, ss = 0.f;
#pragma unroll
    for (int i = 0; i < 4; i++) {
        v[i] = xr[t + 256 * i];
        s += v[i];
        ss += v[i] * v[i];
    }
#pragma unroll
    for (int o = 32; o > 0; o >>= 1) {
        s  += __shfl_down(s, o);
        ss += __shfl_down(ss, o);
    }
    __shared__ float sm[4], sm2[4];
    int wave = t >> 6, lane = t & 63;
    if (lane == 0) { sm[wave] = s; sm2[wave] = ss; }
    __syncthreads();
    s  = sm[0] + sm[1] + sm[2] + sm[3];
    ss = sm2[0] + sm2[1] + sm2[2] + sm2[3];
    float mu  = s * (1.f / TD);
    float var = ss * (1.f / TD) - mu * mu;
    float rstd = rsqrtf(var + 1e-5f);
#pragma unroll
    for (int i = 0; i < 4; i++) {
        int c = t + 256 * i;
        outr[c] = f2bf((v[i] - mu) * rstd * g[c] + b[c]);
    }
}

// --- prep: fused weight convert+transpose (blocks 0..3071) + LN1 (3072..7167) --
__global__ __launch_bounds__(256) void prep_kernel(
    const float* __restrict__ Wqkv, const float* __restrict__ Wo,
    const float* __restrict__ W1,   const float* __restrict__ W2,
    u16* __restrict__ wqkvT, u16* __restrict__ woT,
    u16* __restrict__ w1T,   u16* __restrict__ w2T,
    const float* __restrict__ x, const float* __restrict__ g1,
    const float* __restrict__ b1, u16* __restrict__ hbuf)
{
    int blk = blockIdx.x;
    int t = threadIdx.x;
    if (blk >= 3072) {               // ---- LN1 path ----
        int row = blk - 3072;
        const float* xr = x + (size_t)row * TD;
        u16* outr = hbuf + (size_t)row * TD;
        float v[4];
        float s = 0.f, ss = 0.f;
#pragma unroll
        for (int i = 0; i < 4; i++) {
            v[i] = xr[t + 256 * i];
            s += v[i];
            ss += v[i] * v[i];
        }
#pragma unroll
        for (int o = 32; o > 0; o >>= 1) {
            s  += __shfl_down(s, o);
            ss += __shfl_down(ss, o);
        }
        __shared__ float sm[4], sm2[4];
        int wave = t >> 6, lane = t & 63;
        if (lane == 0) { sm[wave] = s; sm2[wave] = ss; }
        __syncthreads();
        s  = sm[0] + sm[1] + sm[2] + sm[3];
        ss = sm2[0] + sm2[1] + sm2[2] + sm2[3];
        float mu  = s * (1.f / TD);
        float var = ss * (1.f / TD) - mu * mu;
        float rstd = rsqrtf(var + 1e-5f);
#pragma unroll
        for (int i = 0; i < 4; i++) {
            int c = t + 256 * i;
            outr[c] = f2bf((v[i] - mu) * rstd * g1[c] + b1[c]);
        }
        return;
    }
    // ---- weight transpose path ----
    const float* W; u16* Wt; int K, N, local, nx;
    if (blk < 768)       { W = Wqkv; Wt = wqkvT; K = TD;  N = 3 * TD; local = blk;        nx = 48; }
    else if (blk < 1024) { W = Wo;   Wt = woT;   K = TD;  N = TD;     local = blk - 768;  nx = 16; }
    else if (blk < 2048) { W = W1;   Wt = w1T;   K = TD;  N = FFD;    local = blk - 1024; nx = 64; }
    else                 { W = W2;   Wt = w2T;   K = FFD; N = TD;     local = blk - 2048; nx = 16; }
    int n0 = (local % nx) * 64, k0 = (local / nx) * 64;
    __shared__ u16 tile[64][65];
    int c = t & 63, rq = t >> 6;
#pragma unroll
    for (int i = 0; i < 16; i++) {
        int r = rq * 16 + i;
        tile[r][c] = f2bf(W[(size_t)(k0 + r) * N + n0 + c]);
    }
    __syncthreads();
#pragma unroll
    for (int i = 0; i < 16; i++) {
        int r = rq * 16 + i;
        Wt[(size_t)(n0 + r) * K + k0 + c] = tile[c][r];
    }
}

// ---------------- bf16 MFMA GEMM: 128xTN tile, BK k-slab, dbuf LDS -------------
// C[M,N] = A[M,K] @ Bt[N,K]^T + bias, with epilogues.
// Depth-2 pipeline (verified best): one barrier per K-step; prefetch of slab k+1
// issued right AFTER the barrier that publishes slab k. (Depth-3 counted-vmcnt
// was measured WORSE: W1 55.1->57.2us, FETCH +34% -- reverted, R9.)
// LDS swizzle (row = 2*BK bytes, CPR = BK/8 granules): 16B chunk g of row r
// stored at slot g ^ (r&(CPR-1)); frag read ((lq^(lr&(CPR-1)))*16) ^ (h*64).
// CPR=8: 0 conflicts; CPR=4: 2-way (free, m136) - measured 4.2M cnt, acceptable.
// Wave tile = 64 x (TN/2). TN=256 raises LDS arithmetic intensity 32->43 FLOP/B
// (bytes/FLOP = (64+WN)/(64*WN)) and halves block count -> fewer barriers per
// output element. Used for W1 (measured lever test, R10).
// XCD swizzle: tiles remapped so all N-tiles of an M-row land on one XCD's L2.
#define EPI_QKV 0
#define EPI_F32RES 1
#define EPI_GELU 2

template<int EPI, int TN, int BK>
__global__ __launch_bounds__(256) void gemm_mfma(int M, int N, int K,
    const u16* __restrict__ A, const u16* __restrict__ Bt,
    const float* __restrict__ bias, const float* __restrict__ res,
    float* __restrict__ Cf, u16* __restrict__ Cb,
    u16* __restrict__ qb, u16* __restrict__ kb, u16* __restrict__ vb)
{
    constexpr int WN  = TN / 2;               // per-wave N extent (2 waves along N)
    constexpr int NJ  = WN / 16;              // B frags per wave
    constexpr int KH  = BK / 32;              // 32-elem k-halves per slab
    constexpr int CPR = BK / 8;               // 16B chunks per tile-row
    constexpr int ACH = (128 * CPR) / 256;    // A chunks per thread
    constexpr int BCH = (TN  * CPR) / 256;    // B chunks per thread
    constexpr int ASZ = 128 * BK * 2;         // bytes per A buffer
    constexpr int BSZ = TN  * BK * 2;
    __shared__ __align__(16) char smem[2 * (ASZ + BSZ)];

    int t = threadIdx.x;
    int lane = t & 63, w = t >> 6;
    int wm = w >> 1, wn = w & 1;              // 2x2 wave grid: wave = 64(M) x WN(N)
    int lr = lane & 15, lq = lane >> 4;
    // XCD-aware tile remap (gridDim.y % 8 == 0 for all our launches)
    int gx = gridDim.x;
    int lin = blockIdx.x + gx * blockIdx.y;
    int li = lin >> 3;
    int qy = li / gx;
    int ty = (lin & 7) * (gridDim.y >> 3) + qy;
    int tx = li - qy * gx;
    int m0 = ty * 128, n0 = tx * TN;
    int pg = (lq ^ (lr & (CPR - 1))) * 16;    // swizzled frag-read granule offset

    // per-thread staging source pointers (bumped by BK each slab)
    const u16* ap[ACH];
    const u16* bp[BCH];
#pragma unroll
    for (int i = 0; i < ACH; i++) {
        int c = t + 256 * i, r = c / CPR, s = c % CPR;
        int g = s ^ (r & (CPR - 1));
        ap[i] = A + (size_t)(m0 + r) * K + g * 8;
    }
#pragma unroll
    for (int i = 0; i < BCH; i++) {
        int c = t + 256 * i, r = c / CPR, s = c % CPR;
        int g = s ^ (r & (CPR - 1));
        bp[i] = Bt + (size_t)(n0 + r) * K + g * 8;
    }

    f32x4 acc[4][NJ];
#pragma unroll
    for (int i = 0; i < 4; i++)
#pragma unroll
        for (int j = 0; j < NJ; j++) acc[i][j] = (f32x4){0.f, 0.f, 0.f, 0.f};

    // prologue: stage slab 0 into buffer 0
#pragma unroll
    for (int i = 0; i < ACH; i++)
        async16(smem + (t + 256 * i) * 16, ap[i]);
#pragma unroll
    for (int i = 0; i < BCH; i++)
        async16(smem + 2 * ASZ + (t + 256 * i) * 16, bp[i]);

    int nk = K / BK;
    for (int kt = 0; kt < nk; kt++) {
        int cur = kt & 1;
        __syncthreads();                      // slab kt ready; other buffer free
        if (kt + 1 < nk) {                    // prefetch slab kt+1 (drains at next barrier)
            char* An = smem + (1 - cur) * ASZ;
            char* Bn = smem + 2 * ASZ + (1 - cur) * BSZ;
#pragma unroll
            for (int i = 0; i < ACH; i++) {
                ap[i] += BK;
                async16(An + (t + 256 * i) * 16, ap[i]);
            }
#pragma unroll
            for (int i = 0; i < BCH; i++) {
                bp[i] += BK;
                async16(Bn + (t + 256 * i) * 16, bp[i]);
            }
        }
        const char* Ac = smem + cur * ASZ;
        const char* Bc = smem + 2 * ASZ + cur * BSZ;
#pragma unroll
        for (int h = 0; h < KH; h++) {
            bf16x8 af[4], bfr[NJ];
#pragma unroll
            for (int i = 0; i < 4; i++)
                af[i] = *(const bf16x8*)(Ac + (wm * 64 + i * 16 + lr) * (2 * BK) + (pg ^ (h * 64)));
#pragma unroll
            for (int j = 0; j < NJ; j++)
                bfr[j] = *(const bf16x8*)(Bc + (wn * WN + j * 16 + lr) * (2 * BK) + (pg ^ (h * 64)));
#pragma unroll
            for (int i = 0; i < 4; i++)
#pragma unroll
                for (int j = 0; j < NJ; j++)
                    acc[i][j] = __builtin_amdgcn_mfma_f32_16x16x32_bf16(af[i], bfr[j], acc[i][j], 0, 0, 0);
        }
    }

#pragma unroll
    for (int i = 0; i < 4; i++) {
        int rowb = m0 + wm * 64 + i * 16 + lq * 4;
#pragma unroll
        for (int j = 0; j < NJ; j++) {
            int col = n0 + wn * WN + j * 16 + lr;
            float bs = bias[col];
            float vals[4];
#pragma unroll
            for (int r = 0; r < 4; r++) vals[r] = acc[i][j][r] + bs;
            if (EPI == EPI_F32RES) {
#pragma unroll
                for (int r = 0; r < 4; r++) {
                    int rr = rowb + r;
                    Cf[(size_t)rr * N + col] = vals[r] + res[(size_t)rr * N + col];
                }
            } else if (EPI == EPI_GELU) {
#pragma unroll
                for (int r = 0; r < 4; r++)
                    Cb[(size_t)(rowb + r) * N + col] = f2bf(gelu_f(vals[r]));
            } else { // QKV scatter: Q/K [bh][seq][64] (Q pre-scaled), V [bh][64][seq]
                int comp = col >> 10, cw = col & 1023;
                int h = cw >> 6, d = cw & 63;
                int bb0 = rowb >> 11, ts = rowb & 2047;   // rowb%4==0: no batch crossing
                int bh = bb0 * NH + h;
                if (comp == 0) {
#pragma unroll
                    for (int r = 0; r < 4; r++)
                        qb[((size_t)bh * SEQ + ts + r) * HDIM + d] = f2bf(vals[r] * QSCALE);
                } else if (comp == 1) {
#pragma unroll
                    for (int r = 0; r < 4; r++)
                        kb[((size_t)bh * SEQ + ts + r) * HDIM + d] = f2bf(vals[r]);
                } else {
                    ushort4 pk;
                    pk.x = f2bf(vals[0]); pk.y = f2bf(vals[1]);
                    pk.z = f2bf(vals[2]); pk.w = f2bf(vals[3]);
                    *(ushort4*)&vb[((size_t)bh * HDIM + d) * SEQ + ts] = pk;
                }
            }
        }
    }
}

// ---------------- flash attention v4: one q-tile per block, CU-balanced remap --
// qb/kb: [bh][seq][64] bf16 (q pre-scaled by QSCALE); vb: [bh][64][seq] bf16
// 1024 blocks: 4 blocks/CU resident; CU-balanced qt remap; heads XCD-clustered.
// LDS 40KB: QP (Q tile, reused as P buffer) + K dbuf + V dbuf, all XOR-swizzled:
//   chunk g (16B) of row r lives at byte r*128 + ((g ^ (r&7))*16).
// s_setprio(1) wraps MFMA clusters (T5).
__global__ __launch_bounds__(256, 4) void attn_mfma(const u16* __restrict__ qb,
                                                    const u16* __restrict__ kb,
                                                    const u16* __restrict__ vb,
                                                    u16* __restrict__ ctx)
{
    __shared__ __align__(16) char smem[40960];
    char* QP = smem;                        // 8KB Q tile / P buffer (wave-private rows)
    int lin = blockIdx.x + 32 * blockIdx.y;
    int xcd = lin & 7, idx = lin >> 3;      // idx 0..127 within XCD
    int u = idx & 31, v = idx >> 5;         // u: CU slot, v: round
    int bh = xcd + 8 * v;
    int qt = (v & 1) ? u : 31 - u;
    int bb = bh >> 4, h = bh & 15;
    int t = threadIdx.x, lane = t & 63, w = t >> 6;
    int lr = lane & 15, lq = lane >> 4;
    int sw = (lr & 7) * 16;                 // read-side swizzle
    int cA = (lq * 16) ^ sw;                // chunk lq   (k-half 0)
    int cB = (64 | (lq * 16)) ^ sw;         // chunk 4+lq (k-half 1)
    // staging: thread covers LDS chunks t and t+256; swizzled global source
    int c0 = t,        r0 = c0 >> 3, g0 = (c0 & 7) ^ (r0 & 7);
    int c1 = t + 256,  r1 = c1 >> 3, g1 = (c1 & 7) ^ (r1 & 7);
    size_t off0  = (size_t)r0 * 128  + g0 * 16;   // Q/K tiles: 128B per row
    size_t off1  = (size_t)r1 * 128  + g1 * 16;
    size_t voff0 = (size_t)r0 * 4096 + g0 * 16;   // V: row=d, global stride 4096B
    size_t voff1 = (size_t)r1 * 4096 + g1 * 16;

    const char* qg_base = (const char*)qb + (size_t)bh * SEQ * 128;
    const char* kg_base = (const char*)kb + (size_t)bh * SEQ * 128;
    const char* vg_base = (const char*)vb + (size_t)bh * 64 * 4096;

    const char* qg = qg_base + (size_t)qt * 8192;
    async16(QP + c0 * 16, qg + off0);
    async16(QP + c1 * 16, qg + off1);
    async16(smem + 8192 + c0 * 16, kg_base + off0);
    async16(smem + 8192 + c1 * 16, kg_base + off1);
    async16(smem + 24576 + c0 * 16, vg_base + voff0);
    async16(smem + 24576 + c1 * 16, vg_base + voff1);

    float mold = -INFINITY, lsum = 0.f;
    f32x4 o[4];
#pragma unroll
    for (int dj = 0; dj < 4; dj++) o[dj] = (f32x4){0.f, 0.f, 0.f, 0.f};
    bf16x8 bq0, bq1;

    for (int kt = 0; kt <= qt; ++kt) {
        int cur = kt & 1;
        __syncthreads();                // tile kt ready; other buf free
        if (kt < qt) {                  // prefetch kt+1 (drained at next barrier)
            const char* kgn = kg_base + (size_t)(kt + 1) * 8192;
            const char* vgn = vg_base + (size_t)(kt + 1) * 128;
            char* Kn = smem + 8192  + (1 - cur) * 8192;
            char* Vn = smem + 24576 + (1 - cur) * 8192;
            async16(Kn + c0 * 16, kgn + off0);
            async16(Kn + c1 * 16, kgn + off1);
            async16(Vn + c0 * 16, vgn + voff0);
            async16(Vn + c1 * 16, vgn + voff1);
        }
        if (kt == 0) {                  // Q frags -> regs (QP then reused as P)
            const char* qr = QP + (w * 16 + lr) * 128;
            bq0 = *(const bf16x8*)(qr + cA);
            bq1 = *(const bf16x8*)(qr + cB);
        }
        const char* Kc = smem + 8192  + cur * 8192;
        const char* Vc = smem + 24576 + cur * 8192;

        // S^T = K Q^T : lane holds keys j*16+lq*4+r (rows), q = w*16+lr (col)
        float sv[4][4];
        bool diag = (kt == qt);
        __builtin_amdgcn_s_setprio(1);
#pragma unroll
        for (int j = 0; j < 4; ++j) {
            const char* kr = Kc + (j * 16 + lr) * 128;
            bf16x8 ak0 = *(const bf16x8*)(kr + cA);
            bf16x8 ak1 = *(const bf16x8*)(kr + cB);
            f32x4 z = (f32x4){0.f, 0.f, 0.f, 0.f};
            z = __builtin_amdgcn_mfma_f32_16x16x32_bf16(ak0, bq0, z, 0, 0, 0);
            z = __builtin_amdgcn_mfma_f32_16x16x32_bf16(ak1, bq1, z, 0, 0, 0);
#pragma unroll
            for (int r = 0; r < 4; r++) {
                float xv = z[r];
                if (diag && (j * 16 + lq * 4 + r > w * 16 + lr)) xv = -INFINITY;
                sv[j][r] = xv;
            }
        }
        __builtin_amdgcn_s_setprio(0);
        // online softmax in exp2 domain; one q per lane
        float mx = sv[0][0];
#pragma unroll
        for (int j = 0; j < 4; j++)
#pragma unroll
            for (int r = 0; r < 4; r++) mx = fmaxf(mx, sv[j][r]);
        mx = fmaxf(mx, __shfl_xor(mx, 16));
        mx = fmaxf(mx, __shfl_xor(mx, 32));
        float mnew = fmaxf(mold, mx);
        float alpha = exp2f(mold - mnew);
        float rs = 0.f;
        unsigned pk[4][2];
#pragma unroll
        for (int j = 0; j < 4; j++)
#pragma unroll
            for (int hh = 0; hh < 2; hh++) {
                float p0 = exp2f(sv[j][2 * hh]     - mnew);
                float p1 = exp2f(sv[j][2 * hh + 1] - mnew);
                rs += p0 + p1;
                union { float f; unsigned u; } a0, a1;
                a0.f = p0; a1.f = p1;
                // truncation-pack: D = {hi16(p1), hi16(p0)} in ONE v_perm_b32
                pk[j][hh] = __builtin_amdgcn_perm(a1.u, a0.u, 0x07060302u);
            }
        rs += __shfl_xor(rs, 16);
        rs += __shfl_xor(rs, 32);
        lsum = lsum * alpha + rs;
        mold = mnew;
#pragma unroll
        for (int dj = 0; dj < 4; dj++)
#pragma unroll
            for (int r = 0; r < 4; r++) o[dj][r] *= alpha;

        // P^T -> LDS (wave-private rows; no barrier): row q=w*16+lr, b64 writes
        {
            char* pw = QP + (w * 16 + lr) * 128 + (lq & 1) * 8;
#pragma unroll
            for (int j = 0; j < 4; j++) {
                int pos = ((j * 2 + (lq >> 1)) * 16) ^ sw;
                uint2 u2; u2.x = pk[j][0]; u2.y = pk[j][1];
                *(uint2*)(pw + pos) = u2;
            }
        }
        asm volatile("s_waitcnt lgkmcnt(0)" ::: "memory");
        const char* pr = QP + (w * 16 + lr) * 128;
        bf16x8 bp0 = *(const bf16x8*)(pr + cA);
        bf16x8 bp1 = *(const bf16x8*)(pr + cB);
        // O^T += V^T P^T : rows d, cols q
        __builtin_amdgcn_s_setprio(1);
#pragma unroll
        for (int dj = 0; dj < 4; ++dj) {
            const char* vr = Vc + (dj * 16 + lr) * 128;
            bf16x8 av0 = *(const bf16x8*)(vr + cA);
            bf16x8 av1 = *(const bf16x8*)(vr + cB);
            o[dj] = __builtin_amdgcn_mfma_f32_16x16x32_bf16(av0, bp0, o[dj], 0, 0, 0);
            o[dj] = __builtin_amdgcn_mfma_f32_16x16x32_bf16(av1, bp1, o[dj], 0, 0, 0);
        }
        __builtin_amdgcn_s_setprio(0);
    }

    float inv = 1.f / lsum;
    int tok = qt * 64 + w * 16 + lr;
    u16* cp = ctx + ((size_t)(bb * SEQ) + tok) * TD + h * HDIM + lq * 4;
#pragma unroll
    for (int dj = 0; dj < 4; dj++) {
        ushort4 s4;
        s4.x = f2bf(o[dj][0] * inv); s4.y = f2bf(o[dj][1] * inv);
        s4.z = f2bf(o[dj][2] * inv); s4.w = f2bf(o[dj][3] * inv);
        *(ushort4*)(cp + dj * 16) = s4;
    }
}

extern "C" void kernel_launch(void* const* d_in, const int* in_sizes, int n_in,
                              void* d_out, int out_size, void* d_ws, size_t ws_size,
                              hipStream_t stream)
{
    const float* x    = (const float*)d_in[0];
    const float* g1   = (const float*)d_in[1];
    const float* b1   = (const float*)d_in[2];
    const float* Wqkv = (const float*)d_in[3];
    const float* bqkv = (const float*)d_in[4];
    const float* Wo   = (const float*)d_in[5];
    const float* bo   = (const float*)d_in[6];
    const float* g2   = (const float*)d_in[7];
    const float* b2   = (const float*)d_in[8];
    const float* W1   = (const float*)d_in[9];
    const float* b1f  = (const float*)d_in[10];
    const float* W2   = (const float*)d_in[11];
    const float* b2f  = (const float*)d_in[12];
    float* out = (float*)d_out;

    char* ws = (char*)d_ws;
    const size_t MB = 1ull << 20;
    u16* wqkvT = (u16*)(ws + 0 * MB);    // 6 MB  [3072][1024]
    u16* woT   = (u16*)(ws + 6 * MB);    // 2 MB  [1024][1024]
    u16* w1T   = (u16*)(ws + 8 * MB);    // 8 MB  [4096][1024]
    u16* w2T   = (u16*)(ws + 16 * MB);   // 8 MB  [1024][4096]
    u16* qbuf  = (u16*)(ws + 24 * MB);   // 8 MB  [32][2048][64] (pre-scaled)
    u16* kbuf  = (u16*)(ws + 32 * MB);   // 8 MB
    u16* vbuf  = (u16*)(ws + 40 * MB);   // 8 MB  [32][64][2048]
    u16* hbuf  = (u16*)(ws + 48 * MB);   // 8 MB  h then hh
    u16* ctx   = (u16*)(ws + 56 * MB);   // 8 MB
    float* x2  = (float*)(ws + 64 * MB); // 16 MB
    u16* ff1   = (u16*)(ws + 80 * MB);   // 32 MB  -> 112 MB total

    // fused: weight transposes + LN1 (independent work, one dispatch)
    prep_kernel<<<3072 + NROWS, 256, 0, stream>>>(
        Wqkv, Wo, W1, W2, wqkvT, woT, w1T, w2T, x, g1, b1, hbuf);

    gemm_mfma<EPI_QKV, 128, 64><<<dim3(3 * TD / 128, NROWS / 128), 256, 0, stream>>>(
        NROWS, 3 * TD, TD, hbuf, wqkvT, bqkv, nullptr, nullptr, nullptr, qbuf, kbuf, vbuf);
    attn_mfma<<<dim3(32, NB * NH), 256, 0, stream>>>(qbuf, kbuf, vbuf, ctx);
    gemm_mfma<EPI_F32RES, 64, 64><<<dim3(TD / 64, NROWS / 128), 256, 0, stream>>>(
        NROWS, TD, TD, ctx, woT, bo, x, x2, nullptr, nullptr, nullptr, nullptr);
    ln_bf16<<<NROWS, 256, 0, stream>>>(x2, g2, b2, hbuf);
    // W1: TN=256 (wave 64x128, +33% LDS arith intensity), BK=32, 512 blocks
    gemm_mfma<EPI_GELU, 256, 32><<<dim3(FFD / 256, NROWS / 128), 256, 0, stream>>>(
        NROWS, FFD, TD, hbuf, w1T, b1f, nullptr, nullptr, ff1, nullptr, nullptr, nullptr);
    gemm_mfma<EPI_F32RES, 64, 64><<<dim3(TD / 64, NROWS / 128), 256, 0, stream>>>(
        NROWS, TD, FFD, ff1, w2T, b2f, x2, out, nullptr, nullptr, nullptr, nullptr);
}

// Round 18
// 323.339 us; speedup vs baseline: 1.0041x; 1.0041x over previous
//
#include <hip/hip_runtime.h>
#include <math.h>

#define TD 1024      // model dim
#define NH 16        // heads
#define HDIM 64      // head dim
#define SEQ 2048     // seq len
#define NB 2         // batch
#define NROWS 4096   // NB*SEQ
#define FFD 4096     // ffn dim

// 1/sqrt(64) * log2(e): softmax computed in exp2 domain; folded into Q at QKV epilogue
#define QSCALE 0.18033688011112042f

typedef unsigned short u16;
typedef __attribute__((ext_vector_type(8))) short bf16x8;   // 8 bf16 = 4 VGPR
typedef __attribute__((ext_vector_type(4))) float f32x4;    // MFMA acc

__device__ __forceinline__ u16 f2bf(float f) {
    union { float f; unsigned u; } v; v.f = f;
    return (u16)((v.u + 0x7FFFu + ((v.u >> 16) & 1u)) >> 16);
}

// async global->LDS, 16B per lane. LDS dest must be wave-uniform base + lane*16.
__device__ __forceinline__ void async16(void* lds, const void* g) {
    __builtin_amdgcn_global_load_lds(
        (const __attribute__((address_space(1))) unsigned*)g,
        (__attribute__((address_space(3))) unsigned*)lds, 16, 0, 0);
}

// tanh-form GELU (max |err| vs exact erf-GELU ~3e-3; threshold headroom 4x)
__device__ __forceinline__ float gelu_f(float v) {
    float u = 0.7978845608028654f * (v + 0.044715f * v * v * v);
    float e = __expf(2.f * u);
    float th = 1.f - 2.f * __builtin_amdgcn_rcpf(e + 1.f);
    return 0.5f * v * (1.f + th);
}

// ---------------- LayerNorm -> bf16 out: one block per row of 1024 -------------
__global__ __launch_bounds__(256) void ln_bf16(const float* __restrict__ x,
                                               const float* __restrict__ g,
                                               const float* __restrict__ b,
                                               u16* __restrict__ out)
{
    int row = blockIdx.x;
    const float* xr = x + (size_t)row * TD;
    u16* outr = out + (size_t)row * TD;
    int t = threadIdx.x;
    float v[4];
    float s = 0.f, ss = 0.f;
#pragma unroll
    for (int i = 0; i < 4; i++) {
        v[i] = xr[t + 256 * i];
        s += v[i];
        ss += v[i] * v[i];
    }
#pragma unroll
    for (int o = 32; o > 0; o >>= 1) {
        s  += __shfl_down(s, o);
        ss += __shfl_down(ss, o);
    }
    __shared__ float sm[4], sm2[4];
    int wave = t >> 6, lane = t & 63;
    if (lane == 0) { sm[wave] = s; sm2[wave] = ss; }
    __syncthreads();
    s  = sm[0] + sm[1] + sm[2] + sm[3];
    ss = sm2[0] + sm2[1] + sm2[2] + sm2[3];
    float mu  = s * (1.f / TD);
    float var = ss * (1.f / TD) - mu * mu;
    float rstd = rsqrtf(var + 1e-5f);
#pragma unroll
    for (int i = 0; i < 4; i++) {
        int c = t + 256 * i;
        outr[c] = f2bf((v[i] - mu) * rstd * g[c] + b[c]);
    }
}

// --- prep: fused weight convert+transpose (blocks 0..3071) + LN1 (3072..7167) --
__global__ __launch_bounds__(256) void prep_kernel(
    const float* __restrict__ Wqkv, const float* __restrict__ Wo,
    const float* __restrict__ W1,   const float* __restrict__ W2,
    u16* __restrict__ wqkvT, u16* __restrict__ woT,
    u16* __restrict__ w1T,   u16* __restrict__ w2T,
    const float* __restrict__ x, const float* __restrict__ g1,
    const float* __restrict__ b1, u16* __restrict__ hbuf)
{
    int blk = blockIdx.x;
    int t = threadIdx.x;
    if (blk >= 3072) {               // ---- LN1 path ----
        int row = blk - 3072;
        const float* xr = x + (size_t)row * TD;
        u16* outr = hbuf + (size_t)row * TD;
        float v[4];
        float s = 0.f, ss = 0.f;
#pragma unroll
        for (int i = 0; i < 4; i++) {
            v[i] = xr[t + 256 * i];
            s += v[i];
            ss += v[i] * v[i];
        }
#pragma unroll
        for (int o = 32; o > 0; o >>= 1) {
            s  += __shfl_down(s, o);
            ss += __shfl_down(ss, o);
        }
        __shared__ float sm[4], sm2[4];
        int wave = t >> 6, lane = t & 63;
        if (lane == 0) { sm[wave] = s; sm2[wave] = ss; }
        __syncthreads();
        s  = sm[0] + sm[1] + sm[2] + sm[3];
        ss = sm2[0] + sm2[1] + sm2[2] + sm2[3];
        float mu  = s * (1.f / TD);
        float var = ss * (1.f / TD) - mu * mu;
        float rstd = rsqrtf(var + 1e-5f);
#pragma unroll
        for (int i = 0; i < 4; i++) {
            int c = t + 256 * i;
            outr[c] = f2bf((v[i] - mu) * rstd * g1[c] + b1[c]);
        }
        return;
    }
    // ---- weight transpose path ----
    const float* W; u16* Wt; int K, N, local, nx;
    if (blk < 768)       { W = Wqkv; Wt = wqkvT; K = TD;  N = 3 * TD; local = blk;        nx = 48; }
    else if (blk < 1024) { W = Wo;   Wt = woT;   K = TD;  N = TD;     local = blk - 768;  nx = 16; }
    else if (blk < 2048) { W = W1;   Wt = w1T;   K = TD;  N = FFD;    local = blk - 1024; nx = 64; }
    else                 { W = W2;   Wt = w2T;   K = FFD; N = TD;     local = blk - 2048; nx = 16; }
    int n0 = (local % nx) * 64, k0 = (local / nx) * 64;
    __shared__ u16 tile[64][65];
    int c = t & 63, rq = t >> 6;
#pragma unroll
    for (int i = 0; i < 16; i++) {
        int r = rq * 16 + i;
        tile[r][c] = f2bf(W[(size_t)(k0 + r) * N + n0 + c]);
    }
    __syncthreads();
#pragma unroll
    for (int i = 0; i < 16; i++) {
        int r = rq * 16 + i;
        Wt[(size_t)(n0 + r) * K + k0 + c] = tile[c][r];
    }
}

// ---------------- bf16 MFMA GEMM: 128xTN tile, BK k-slab, dbuf LDS -------------
// C[M,N] = A[M,K] @ Bt[N,K]^T + bias, with epilogues.
// Depth-2 pipeline (verified best): one barrier per K-step; prefetch of slab k+1
// issued right AFTER the barrier that publishes slab k.
// Measured W1-dispatch ladder (R3/R6/R9/R16): TN128/BK64=64.0us, TN128/BK32=55.1
// (BEST), depth-3=57.2 (reverted), TN256/BK32=67.6 (VGPR 144, occupancy 10% --
// reverted; TLP/blocks-per-CU dominates per-wave reuse for this structure).
// LDS swizzle (row = 2*BK bytes, CPR = BK/8 granules): 16B chunk g of row r
// stored at slot g ^ (r&(CPR-1)); frag read ((lq^(lr&(CPR-1)))*16) ^ (h*64).
// CPR=8: 0 conflicts; CPR=4: 2-way (free, m136).
// XCD swizzle: tiles remapped so all N-tiles of an M-row land on one XCD's L2.
#define EPI_QKV 0
#define EPI_F32RES 1
#define EPI_GELU 2

template<int EPI, int TN, int BK>
__global__ __launch_bounds__(256) void gemm_mfma(int M, int N, int K,
    const u16* __restrict__ A, const u16* __restrict__ Bt,
    const float* __restrict__ bias, const float* __restrict__ res,
    float* __restrict__ Cf, u16* __restrict__ Cb,
    u16* __restrict__ qb, u16* __restrict__ kb, u16* __restrict__ vb)
{
    constexpr int WN  = TN / 2;               // per-wave N extent (2 waves along N)
    constexpr int NJ  = WN / 16;              // B frags per wave
    constexpr int KH  = BK / 32;              // 32-elem k-halves per slab
    constexpr int CPR = BK / 8;               // 16B chunks per tile-row
    constexpr int ACH = (128 * CPR) / 256;    // A chunks per thread
    constexpr int BCH = (TN  * CPR) / 256;    // B chunks per thread
    constexpr int ASZ = 128 * BK * 2;         // bytes per A buffer
    constexpr int BSZ = TN  * BK * 2;
    __shared__ __align__(16) char smem[2 * (ASZ + BSZ)];

    int t = threadIdx.x;
    int lane = t & 63, w = t >> 6;
    int wm = w >> 1, wn = w & 1;              // 2x2 wave grid: wave = 64(M) x WN(N)
    int lr = lane & 15, lq = lane >> 4;
    // XCD-aware tile remap (gridDim.y % 8 == 0 for all our launches)
    int gx = gridDim.x;
    int lin = blockIdx.x + gx * blockIdx.y;
    int li = lin >> 3;
    int qy = li / gx;
    int ty = (lin & 7) * (gridDim.y >> 3) + qy;
    int tx = li - qy * gx;
    int m0 = ty * 128, n0 = tx * TN;
    int pg = (lq ^ (lr & (CPR - 1))) * 16;    // swizzled frag-read granule offset

    // per-thread staging source pointers (bumped by BK each slab)
    const u16* ap[ACH];
    const u16* bp[BCH];
#pragma unroll
    for (int i = 0; i < ACH; i++) {
        int c = t + 256 * i, r = c / CPR, s = c % CPR;
        int g = s ^ (r & (CPR - 1));
        ap[i] = A + (size_t)(m0 + r) * K + g * 8;
    }
#pragma unroll
    for (int i = 0; i < BCH; i++) {
        int c = t + 256 * i, r = c / CPR, s = c % CPR;
        int g = s ^ (r & (CPR - 1));
        bp[i] = Bt + (size_t)(n0 + r) * K + g * 8;
    }

    f32x4 acc[4][NJ];
#pragma unroll
    for (int i = 0; i < 4; i++)
#pragma unroll
        for (int j = 0; j < NJ; j++) acc[i][j] = (f32x4){0.f, 0.f, 0.f, 0.f};

    // prologue: stage slab 0 into buffer 0
#pragma unroll
    for (int i = 0; i < ACH; i++)
        async16(smem + (t + 256 * i) * 16, ap[i]);
#pragma unroll
    for (int i = 0; i < BCH; i++)
        async16(smem + 2 * ASZ + (t + 256 * i) * 16, bp[i]);

    int nk = K / BK;
    for (int kt = 0; kt < nk; kt++) {
        int cur = kt & 1;
        __syncthreads();                      // slab kt ready; other buffer free
        if (kt + 1 < nk) {                    // prefetch slab kt+1 (drains at next barrier)
            char* An = smem + (1 - cur) * ASZ;
            char* Bn = smem + 2 * ASZ + (1 - cur) * BSZ;
#pragma unroll
            for (int i = 0; i < ACH; i++) {
                ap[i] += BK;
                async16(An + (t + 256 * i) * 16, ap[i]);
            }
#pragma unroll
            for (int i = 0; i < BCH; i++) {
                bp[i] += BK;
                async16(Bn + (t + 256 * i) * 16, bp[i]);
            }
        }
        const char* Ac = smem + cur * ASZ;
        const char* Bc = smem + 2 * ASZ + cur * BSZ;
#pragma unroll
        for (int h = 0; h < KH; h++) {
            bf16x8 af[4], bfr[NJ];
#pragma unroll
            for (int i = 0; i < 4; i++)
                af[i] = *(const bf16x8*)(Ac + (wm * 64 + i * 16 + lr) * (2 * BK) + (pg ^ (h * 64)));
#pragma unroll
            for (int j = 0; j < NJ; j++)
                bfr[j] = *(const bf16x8*)(Bc + (wn * WN + j * 16 + lr) * (2 * BK) + (pg ^ (h * 64)));
#pragma unroll
            for (int i = 0; i < 4; i++)
#pragma unroll
                for (int j = 0; j < NJ; j++)
                    acc[i][j] = __builtin_amdgcn_mfma_f32_16x16x32_bf16(af[i], bfr[j], acc[i][j], 0, 0, 0);
        }
    }

#pragma unroll
    for (int i = 0; i < 4; i++) {
        int rowb = m0 + wm * 64 + i * 16 + lq * 4;
#pragma unroll
        for (int j = 0; j < NJ; j++) {
            int col = n0 + wn * WN + j * 16 + lr;
            float bs = bias[col];
            float vals[4];
#pragma unroll
            for (int r = 0; r < 4; r++) vals[r] = acc[i][j][r] + bs;
            if (EPI == EPI_F32RES) {
#pragma unroll
                for (int r = 0; r < 4; r++) {
                    int rr = rowb + r;
                    Cf[(size_t)rr * N + col] = vals[r] + res[(size_t)rr * N + col];
                }
            } else if (EPI == EPI_GELU) {
#pragma unroll
                for (int r = 0; r < 4; r++)
                    Cb[(size_t)(rowb + r) * N + col] = f2bf(gelu_f(vals[r]));
            } else { // QKV scatter: Q/K [bh][seq][64] (Q pre-scaled), V [bh][64][seq]
                int comp = col >> 10, cw = col & 1023;
                int h = cw >> 6, d = cw & 63;
                int bb0 = rowb >> 11, ts = rowb & 2047;   // rowb%4==0: no batch crossing
                int bh = bb0 * NH + h;
                if (comp == 0) {
#pragma unroll
                    for (int r = 0; r < 4; r++)
                        qb[((size_t)bh * SEQ + ts + r) * HDIM + d] = f2bf(vals[r] * QSCALE);
                } else if (comp == 1) {
#pragma unroll
                    for (int r = 0; r < 4; r++)
                        kb[((size_t)bh * SEQ + ts + r) * HDIM + d] = f2bf(vals[r]);
                } else {
                    ushort4 pk;
                    pk.x = f2bf(vals[0]); pk.y = f2bf(vals[1]);
                    pk.z = f2bf(vals[2]); pk.w = f2bf(vals[3]);
                    *(ushort4*)&vb[((size_t)bh * HDIM + d) * SEQ + ts] = pk;
                }
            }
        }
    }
}

// ---------------- flash attention v4: one q-tile per block, CU-balanced remap --
// qb/kb: [bh][seq][64] bf16 (q pre-scaled by QSCALE); vb: [bh][64][seq] bf16
// 1024 blocks: 4 blocks/CU resident; CU-balanced qt remap; heads XCD-clustered.
// LDS 40KB: QP (Q tile, reused as P buffer) + K dbuf + V dbuf, all XOR-swizzled:
//   chunk g (16B) of row r lives at byte r*128 + ((g ^ (r&7))*16).
// s_setprio(1) wraps MFMA clusters (T5).
__global__ __launch_bounds__(256, 4) void attn_mfma(const u16* __restrict__ qb,
                                                    const u16* __restrict__ kb,
                                                    const u16* __restrict__ vb,
                                                    u16* __restrict__ ctx)
{
    __shared__ __align__(16) char smem[40960];
    char* QP = smem;                        // 8KB Q tile / P buffer (wave-private rows)
    int lin = blockIdx.x + 32 * blockIdx.y;
    int xcd = lin & 7, idx = lin >> 3;      // idx 0..127 within XCD
    int u = idx & 31, v = idx >> 5;         // u: CU slot, v: round
    int bh = xcd + 8 * v;
    int qt = (v & 1) ? u : 31 - u;
    int bb = bh >> 4, h = bh & 15;
    int t = threadIdx.x, lane = t & 63, w = t >> 6;
    int lr = lane & 15, lq = lane >> 4;
    int sw = (lr & 7) * 16;                 // read-side swizzle
    int cA = (lq * 16) ^ sw;                // chunk lq   (k-half 0)
    int cB = (64 | (lq * 16)) ^ sw;         // chunk 4+lq (k-half 1)
    // staging: thread covers LDS chunks t and t+256; swizzled global source
    int c0 = t,        r0 = c0 >> 3, g0 = (c0 & 7) ^ (r0 & 7);
    int c1 = t + 256,  r1 = c1 >> 3, g1 = (c1 & 7) ^ (r1 & 7);
    size_t off0  = (size_t)r0 * 128  + g0 * 16;   // Q/K tiles: 128B per row
    size_t off1  = (size_t)r1 * 128  + g1 * 16;
    size_t voff0 = (size_t)r0 * 4096 + g0 * 16;   // V: row=d, global stride 4096B
    size_t voff1 = (size_t)r1 * 4096 + g1 * 16;

    const char* qg_base = (const char*)qb + (size_t)bh * SEQ * 128;
    const char* kg_base = (const char*)kb + (size_t)bh * SEQ * 128;
    const char* vg_base = (const char*)vb + (size_t)bh * 64 * 4096;

    const char* qg = qg_base + (size_t)qt * 8192;
    async16(QP + c0 * 16, qg + off0);
    async16(QP + c1 * 16, qg + off1);
    async16(smem + 8192 + c0 * 16, kg_base + off0);
    async16(smem + 8192 + c1 * 16, kg_base + off1);
    async16(smem + 24576 + c0 * 16, vg_base + voff0);
    async16(smem + 24576 + c1 * 16, vg_base + voff1);

    float mold = -INFINITY, lsum = 0.f;
    f32x4 o[4];
#pragma unroll
    for (int dj = 0; dj < 4; dj++) o[dj] = (f32x4){0.f, 0.f, 0.f, 0.f};
    bf16x8 bq0, bq1;

    for (int kt = 0; kt <= qt; ++kt) {
        int cur = kt & 1;
        __syncthreads();                // tile kt ready; other buf free
        if (kt < qt) {                  // prefetch kt+1 (drained at next barrier)
            const char* kgn = kg_base + (size_t)(kt + 1) * 8192;
            const char* vgn = vg_base + (size_t)(kt + 1) * 128;
            char* Kn = smem + 8192  + (1 - cur) * 8192;
            char* Vn = smem + 24576 + (1 - cur) * 8192;
            async16(Kn + c0 * 16, kgn + off0);
            async16(Kn + c1 * 16, kgn + off1);
            async16(Vn + c0 * 16, vgn + voff0);
            async16(Vn + c1 * 16, vgn + voff1);
        }
        if (kt == 0) {                  // Q frags -> regs (QP then reused as P)
            const char* qr = QP + (w * 16 + lr) * 128;
            bq0 = *(const bf16x8*)(qr + cA);
            bq1 = *(const bf16x8*)(qr + cB);
        }
        const char* Kc = smem + 8192  + cur * 8192;
        const char* Vc = smem + 24576 + cur * 8192;

        // S^T = K Q^T : lane holds keys j*16+lq*4+r (rows), q = w*16+lr (col)
        float sv[4][4];
        bool diag = (kt == qt);
        __builtin_amdgcn_s_setprio(1);
#pragma unroll
        for (int j = 0; j < 4; ++j) {
            const char* kr = Kc + (j * 16 + lr) * 128;
            bf16x8 ak0 = *(const bf16x8*)(kr + cA);
            bf16x8 ak1 = *(const bf16x8*)(kr + cB);
            f32x4 z = (f32x4){0.f, 0.f, 0.f, 0.f};
            z = __builtin_amdgcn_mfma_f32_16x16x32_bf16(ak0, bq0, z, 0, 0, 0);
            z = __builtin_amdgcn_mfma_f32_16x16x32_bf16(ak1, bq1, z, 0, 0, 0);
#pragma unroll
            for (int r = 0; r < 4; r++) {
                float xv = z[r];
                if (diag && (j * 16 + lq * 4 + r > w * 16 + lr)) xv = -INFINITY;
                sv[j][r] = xv;
            }
        }
        __builtin_amdgcn_s_setprio(0);
        // online softmax in exp2 domain; one q per lane
        float mx = sv[0][0];
#pragma unroll
        for (int j = 0; j < 4; j++)
#pragma unroll
            for (int r = 0; r < 4; r++) mx = fmaxf(mx, sv[j][r]);
        mx = fmaxf(mx, __shfl_xor(mx, 16));
        mx = fmaxf(mx, __shfl_xor(mx, 32));
        float mnew = fmaxf(mold, mx);
        float alpha = exp2f(mold - mnew);
        float rs = 0.f;
        unsigned pk[4][2];
#pragma unroll
        for (int j = 0; j < 4; j++)
#pragma unroll
            for (int hh = 0; hh < 2; hh++) {
                float p0 = exp2f(sv[j][2 * hh]     - mnew);
                float p1 = exp2f(sv[j][2 * hh + 1] - mnew);
                rs += p0 + p1;
                union { float f; unsigned u; } a0, a1;
                a0.f = p0; a1.f = p1;
                // truncation-pack: D = {hi16(p1), hi16(p0)} in ONE v_perm_b32
                pk[j][hh] = __builtin_amdgcn_perm(a1.u, a0.u, 0x07060302u);
            }
        rs += __shfl_xor(rs, 16);
        rs += __shfl_xor(rs, 32);
        lsum = lsum * alpha + rs;
        mold = mnew;
#pragma unroll
        for (int dj = 0; dj < 4; dj++)
#pragma unroll
            for (int r = 0; r < 4; r++) o[dj][r] *= alpha;

        // P^T -> LDS (wave-private rows; no barrier): row q=w*16+lr, b64 writes
        {
            char* pw = QP + (w * 16 + lr) * 128 + (lq & 1) * 8;
#pragma unroll
            for (int j = 0; j < 4; j++) {
                int pos = ((j * 2 + (lq >> 1)) * 16) ^ sw;
                uint2 u2; u2.x = pk[j][0]; u2.y = pk[j][1];
                *(uint2*)(pw + pos) = u2;
            }
        }
        asm volatile("s_waitcnt lgkmcnt(0)" ::: "memory");
        const char* pr = QP + (w * 16 + lr) * 128;
        bf16x8 bp0 = *(const bf16x8*)(pr + cA);
        bf16x8 bp1 = *(const bf16x8*)(pr + cB);
        // O^T += V^T P^T : rows d, cols q
        __builtin_amdgcn_s_setprio(1);
#pragma unroll
        for (int dj = 0; dj < 4; ++dj) {
            const char* vr = Vc + (dj * 16 + lr) * 128;
            bf16x8 av0 = *(const bf16x8*)(vr + cA);
            bf16x8 av1 = *(const bf16x8*)(vr + cB);
            o[dj] = __builtin_amdgcn_mfma_f32_16x16x32_bf16(av0, bp0, o[dj], 0, 0, 0);
            o[dj] = __builtin_amdgcn_mfma_f32_16x16x32_bf16(av1, bp1, o[dj], 0, 0, 0);
        }
        __builtin_amdgcn_s_setprio(0);
    }

    float inv = 1.f / lsum;
    int tok = qt * 64 + w * 16 + lr;
    u16* cp = ctx + ((size_t)(bb * SEQ) + tok) * TD + h * HDIM + lq * 4;
#pragma unroll
    for (int dj = 0; dj < 4; dj++) {
        ushort4 s4;
        s4.x = f2bf(o[dj][0] * inv); s4.y = f2bf(o[dj][1] * inv);
        s4.z = f2bf(o[dj][2] * inv); s4.w = f2bf(o[dj][3] * inv);
        *(ushort4*)(cp + dj * 16) = s4;
    }
}

extern "C" void kernel_launch(void* const* d_in, const int* in_sizes, int n_in,
                              void* d_out, int out_size, void* d_ws, size_t ws_size,
                              hipStream_t stream)
{
    const float* x    = (const float*)d_in[0];
    const float* g1   = (const float*)d_in[1];
    const float* b1   = (const float*)d_in[2];
    const float* Wqkv = (const float*)d_in[3];
    const float* bqkv = (const float*)d_in[4];
    const float* Wo   = (const float*)d_in[5];
    const float* bo   = (const float*)d_in[6];
    const float* g2   = (const float*)d_in[7];
    const float* b2   = (const float*)d_in[8];
    const float* W1   = (const float*)d_in[9];
    const float* b1f  = (const float*)d_in[10];
    const float* W2   = (const float*)d_in[11];
    const float* b2f  = (const float*)d_in[12];
    float* out = (float*)d_out;

    char* ws = (char*)d_ws;
    const size_t MB = 1ull << 20;
    u16* wqkvT = (u16*)(ws + 0 * MB);    // 6 MB  [3072][1024]
    u16* woT   = (u16*)(ws + 6 * MB);    // 2 MB  [1024][1024]
    u16* w1T   = (u16*)(ws + 8 * MB);    // 8 MB  [4096][1024]
    u16* w2T   = (u16*)(ws + 16 * MB);   // 8 MB  [1024][4096]
    u16* qbuf  = (u16*)(ws + 24 * MB);   // 8 MB  [32][2048][64] (pre-scaled)
    u16* kbuf  = (u16*)(ws + 32 * MB);   // 8 MB
    u16* vbuf  = (u16*)(ws + 40 * MB);   // 8 MB  [32][64][2048]
    u16* hbuf  = (u16*)(ws + 48 * MB);   // 8 MB  h then hh
    u16* ctx   = (u16*)(ws + 56 * MB);   // 8 MB
    float* x2  = (float*)(ws + 64 * MB); // 16 MB
    u16* ff1   = (u16*)(ws + 80 * MB);   // 32 MB  -> 112 MB total

    // fused: weight transposes + LN1 (independent work, one dispatch)
    prep_kernel<<<3072 + NROWS, 256, 0, stream>>>(
        Wqkv, Wo, W1, W2, wqkvT, woT, w1T, w2T, x, g1, b1, hbuf);

    gemm_mfma<EPI_QKV, 128, 64><<<dim3(3 * TD / 128, NROWS / 128), 256, 0, stream>>>(
        NROWS, 3 * TD, TD, hbuf, wqkvT, bqkv, nullptr, nullptr, nullptr, qbuf, kbuf, vbuf);
    attn_mfma<<<dim3(32, NB * NH), 256, 0, stream>>>(qbuf, kbuf, vbuf, ctx);
    gemm_mfma<EPI_F32RES, 64, 64><<<dim3(TD / 64, NROWS / 128), 256, 0, stream>>>(
        NROWS, TD, TD, ctx, woT, bo, x, x2, nullptr, nullptr, nullptr, nullptr);
    ln_bf16<<<NROWS, 256, 0, stream>>>(x2, g2, b2, hbuf);
    // W1: TN=128/BK=32 (measured best: 55.1us; TN256 regressed to 67.6, R16)
    gemm_mfma<EPI_GELU, 128, 32><<<dim3(FFD / 128, NROWS / 128), 256, 0, stream>>>(
        NROWS, FFD, TD, hbuf, w1T, b1f, nullptr, nullptr, ff1, nullptr, nullptr, nullptr);
    gemm_mfma<EPI_F32RES, 64, 64><<<dim3(TD / 64, NROWS / 128), 256, 0, stream>>>(
        NROWS, TD, FFD, ff1, w2T, b2f, x2, out, nullptr, nullptr, nullptr, nullptr);
}

// Round 19
// 320.206 us; speedup vs baseline: 1.0139x; 1.0098x over previous
//
#include <hip/hip_runtime.h>
#include <math.h>

#define TD 1024      // model dim
#define NH 16        // heads
#define HDIM 64      // head dim
#define SEQ 2048     // seq len
#define NB 2         // batch
#define NROWS 4096   // NB*SEQ
#define FFD 4096     // ffn dim

// 1/sqrt(64) * log2(e): softmax computed in exp2 domain; folded into Q at QKV epilogue
#define QSCALE 0.18033688011112042f

typedef unsigned short u16;
typedef __attribute__((ext_vector_type(8))) short bf16x8;   // 8 bf16 = 4 VGPR
typedef __attribute__((ext_vector_type(4))) float f32x4;    // MFMA acc

__device__ __forceinline__ u16 f2bf(float f) {
    union { float f; unsigned u; } v; v.f = f;
    return (u16)((v.u + 0x7FFFu + ((v.u >> 16) & 1u)) >> 16);
}

// async global->LDS, 16B per lane. LDS dest must be wave-uniform base + lane*16.
__device__ __forceinline__ void async16(void* lds, const void* g) {
    __builtin_amdgcn_global_load_lds(
        (const __attribute__((address_space(1))) unsigned*)g,
        (__attribute__((address_space(3))) unsigned*)lds, 16, 0, 0);
}

// tanh-form GELU (max |err| vs exact erf-GELU ~3e-3; threshold headroom 4x)
__device__ __forceinline__ float gelu_f(float v) {
    float u = 0.7978845608028654f * (v + 0.044715f * v * v * v);
    float e = __expf(2.f * u);
    float th = 1.f - 2.f * __builtin_amdgcn_rcpf(e + 1.f);
    return 0.5f * v * (1.f + th);
}

// ---------------- LayerNorm -> bf16 out: one block per row of 1024 -------------
__global__ __launch_bounds__(256) void ln_bf16(const float* __restrict__ x,
                                               const float* __restrict__ g,
                                               const float* __restrict__ b,
                                               u16* __restrict__ out)
{
    int row = blockIdx.x;
    const float* xr = x + (size_t)row * TD;
    u16* outr = out + (size_t)row * TD;
    int t = threadIdx.x;
    float v[4];
    float s = 0.f, ss = 0.f;
#pragma unroll
    for (int i = 0; i < 4; i++) {
        v[i] = xr[t + 256 * i];
        s += v[i];
        ss += v[i] * v[i];
    }
#pragma unroll
    for (int o = 32; o > 0; o >>= 1) {
        s  += __shfl_down(s, o);
        ss += __shfl_down(ss, o);
    }
    __shared__ float sm[4], sm2[4];
    int wave = t >> 6, lane = t & 63;
    if (lane == 0) { sm[wave] = s; sm2[wave] = ss; }
    __syncthreads();
    s  = sm[0] + sm[1] + sm[2] + sm[3];
    ss = sm2[0] + sm2[1] + sm2[2] + sm2[3];
    float mu  = s * (1.f / TD);
    float var = ss * (1.f / TD) - mu * mu;
    float rstd = rsqrtf(var + 1e-5f);
#pragma unroll
    for (int i = 0; i < 4; i++) {
        int c = t + 256 * i;
        outr[c] = f2bf((v[i] - mu) * rstd * g[c] + b[c]);
    }
}

// --- prep: fused weight convert+transpose (blocks 0..3071) + LN1 (3072..7167) --
__global__ __launch_bounds__(256) void prep_kernel(
    const float* __restrict__ Wqkv, const float* __restrict__ Wo,
    const float* __restrict__ W1,   const float* __restrict__ W2,
    u16* __restrict__ wqkvT, u16* __restrict__ woT,
    u16* __restrict__ w1T,   u16* __restrict__ w2T,
    const float* __restrict__ x, const float* __restrict__ g1,
    const float* __restrict__ b1, u16* __restrict__ hbuf)
{
    int blk = blockIdx.x;
    int t = threadIdx.x;
    if (blk >= 3072) {               // ---- LN1 path ----
        int row = blk - 3072;
        const float* xr = x + (size_t)row * TD;
        u16* outr = hbuf + (size_t)row * TD;
        float v[4];
        float s = 0.f, ss = 0.f;
#pragma unroll
        for (int i = 0; i < 4; i++) {
            v[i] = xr[t + 256 * i];
            s += v[i];
            ss += v[i] * v[i];
        }
#pragma unroll
        for (int o = 32; o > 0; o >>= 1) {
            s  += __shfl_down(s, o);
            ss += __shfl_down(ss, o);
        }
        __shared__ float sm[4], sm2[4];
        int wave = t >> 6, lane = t & 63;
        if (lane == 0) { sm[wave] = s; sm2[wave] = ss; }
        __syncthreads();
        s  = sm[0] + sm[1] + sm[2] + sm[3];
        ss = sm2[0] + sm2[1] + sm2[2] + sm2[3];
        float mu  = s * (1.f / TD);
        float var = ss * (1.f / TD) - mu * mu;
        float rstd = rsqrtf(var + 1e-5f);
#pragma unroll
        for (int i = 0; i < 4; i++) {
            int c = t + 256 * i;
            outr[c] = f2bf((v[i] - mu) * rstd * g1[c] + b1[c]);
        }
        return;
    }
    // ---- weight transpose path ----
    const float* W; u16* Wt; int K, N, local, nx;
    if (blk < 768)       { W = Wqkv; Wt = wqkvT; K = TD;  N = 3 * TD; local = blk;        nx = 48; }
    else if (blk < 1024) { W = Wo;   Wt = woT;   K = TD;  N = TD;     local = blk - 768;  nx = 16; }
    else if (blk < 2048) { W = W1;   Wt = w1T;   K = TD;  N = FFD;    local = blk - 1024; nx = 64; }
    else                 { W = W2;   Wt = w2T;   K = FFD; N = TD;     local = blk - 2048; nx = 16; }
    int n0 = (local % nx) * 64, k0 = (local / nx) * 64;
    __shared__ u16 tile[64][65];
    int c = t & 63, rq = t >> 6;
#pragma unroll
    for (int i = 0; i < 16; i++) {
        int r = rq * 16 + i;
        tile[r][c] = f2bf(W[(size_t)(k0 + r) * N + n0 + c]);
    }
    __syncthreads();
#pragma unroll
    for (int i = 0; i < 16; i++) {
        int r = rq * 16 + i;
        Wt[(size_t)(n0 + r) * K + k0 + c] = tile[c][r];
    }
}

// ---------------- bf16 MFMA GEMM: 128xTN tile, BK k-slab, dbuf LDS -------------
// (legacy 2-barrier structure; measured ceiling W1=55.1us. Kept for QKV/Wo/W2.)
#define EPI_QKV 0
#define EPI_F32RES 1
#define EPI_GELU 2

template<int EPI, int TN, int BK>
__global__ __launch_bounds__(256) void gemm_mfma(int M, int N, int K,
    const u16* __restrict__ A, const u16* __restrict__ Bt,
    const float* __restrict__ bias, const float* __restrict__ res,
    float* __restrict__ Cf, u16* __restrict__ Cb,
    u16* __restrict__ qb, u16* __restrict__ kb, u16* __restrict__ vb)
{
    constexpr int WN  = TN / 2;               // per-wave N extent (2 waves along N)
    constexpr int NJ  = WN / 16;              // B frags per wave
    constexpr int KH  = BK / 32;              // 32-elem k-halves per slab
    constexpr int CPR = BK / 8;               // 16B chunks per tile-row
    constexpr int ACH = (128 * CPR) / 256;    // A chunks per thread
    constexpr int BCH = (TN  * CPR) / 256;    // B chunks per thread
    constexpr int ASZ = 128 * BK * 2;         // bytes per A buffer
    constexpr int BSZ = TN  * BK * 2;
    __shared__ __align__(16) char smem[2 * (ASZ + BSZ)];

    int t = threadIdx.x;
    int lane = t & 63, w = t >> 6;
    int wm = w >> 1, wn = w & 1;              // 2x2 wave grid: wave = 64(M) x WN(N)
    int lr = lane & 15, lq = lane >> 4;
    int gx = gridDim.x;
    int lin = blockIdx.x + gx * blockIdx.y;
    int li = lin >> 3;
    int qy = li / gx;
    int ty = (lin & 7) * (gridDim.y >> 3) + qy;
    int tx = li - qy * gx;
    int m0 = ty * 128, n0 = tx * TN;
    int pg = (lq ^ (lr & (CPR - 1))) * 16;    // swizzled frag-read granule offset

    const u16* ap[ACH];
    const u16* bp[BCH];
#pragma unroll
    for (int i = 0; i < ACH; i++) {
        int c = t + 256 * i, r = c / CPR, s = c % CPR;
        int g = s ^ (r & (CPR - 1));
        ap[i] = A + (size_t)(m0 + r) * K + g * 8;
    }
#pragma unroll
    for (int i = 0; i < BCH; i++) {
        int c = t + 256 * i, r = c / CPR, s = c % CPR;
        int g = s ^ (r & (CPR - 1));
        bp[i] = Bt + (size_t)(n0 + r) * K + g * 8;
    }

    f32x4 acc[4][NJ];
#pragma unroll
    for (int i = 0; i < 4; i++)
#pragma unroll
        for (int j = 0; j < NJ; j++) acc[i][j] = (f32x4){0.f, 0.f, 0.f, 0.f};

#pragma unroll
    for (int i = 0; i < ACH; i++)
        async16(smem + (t + 256 * i) * 16, ap[i]);
#pragma unroll
    for (int i = 0; i < BCH; i++)
        async16(smem + 2 * ASZ + (t + 256 * i) * 16, bp[i]);

    int nk = K / BK;
    for (int kt = 0; kt < nk; kt++) {
        int cur = kt & 1;
        __syncthreads();
        if (kt + 1 < nk) {
            char* An = smem + (1 - cur) * ASZ;
            char* Bn = smem + 2 * ASZ + (1 - cur) * BSZ;
#pragma unroll
            for (int i = 0; i < ACH; i++) {
                ap[i] += BK;
                async16(An + (t + 256 * i) * 16, ap[i]);
            }
#pragma unroll
            for (int i = 0; i < BCH; i++) {
                bp[i] += BK;
                async16(Bn + (t + 256 * i) * 16, bp[i]);
            }
        }
        const char* Ac = smem + cur * ASZ;
        const char* Bc = smem + 2 * ASZ + cur * BSZ;
#pragma unroll
        for (int h = 0; h < KH; h++) {
            bf16x8 af[4], bfr[NJ];
#pragma unroll
            for (int i = 0; i < 4; i++)
                af[i] = *(const bf16x8*)(Ac + (wm * 64 + i * 16 + lr) * (2 * BK) + (pg ^ (h * 64)));
#pragma unroll
            for (int j = 0; j < NJ; j++)
                bfr[j] = *(const bf16x8*)(Bc + (wn * WN + j * 16 + lr) * (2 * BK) + (pg ^ (h * 64)));
#pragma unroll
            for (int i = 0; i < 4; i++)
#pragma unroll
                for (int j = 0; j < NJ; j++)
                    acc[i][j] = __builtin_amdgcn_mfma_f32_16x16x32_bf16(af[i], bfr[j], acc[i][j], 0, 0, 0);
        }
    }

#pragma unroll
    for (int i = 0; i < 4; i++) {
        int rowb = m0 + wm * 64 + i * 16 + lq * 4;
#pragma unroll
        for (int j = 0; j < NJ; j++) {
            int col = n0 + wn * WN + j * 16 + lr;
            float bs = bias[col];
            float vals[4];
#pragma unroll
            for (int r = 0; r < 4; r++) vals[r] = acc[i][j][r] + bs;
            if (EPI == EPI_F32RES) {
#pragma unroll
                for (int r = 0; r < 4; r++) {
                    int rr = rowb + r;
                    Cf[(size_t)rr * N + col] = vals[r] + res[(size_t)rr * N + col];
                }
            } else if (EPI == EPI_GELU) {
#pragma unroll
                for (int r = 0; r < 4; r++)
                    Cb[(size_t)(rowb + r) * N + col] = f2bf(gelu_f(vals[r]));
            } else { // QKV scatter: Q/K [bh][seq][64] (Q pre-scaled), V [bh][64][seq]
                int comp = col >> 10, cw = col & 1023;
                int h = cw >> 6, d = cw & 63;
                int bb0 = rowb >> 11, ts = rowb & 2047;   // rowb%4==0: no batch crossing
                int bh = bb0 * NH + h;
                if (comp == 0) {
#pragma unroll
                    for (int r = 0; r < 4; r++)
                        qb[((size_t)bh * SEQ + ts + r) * HDIM + d] = f2bf(vals[r] * QSCALE);
                } else if (comp == 1) {
#pragma unroll
                    for (int r = 0; r < 4; r++)
                        kb[((size_t)bh * SEQ + ts + r) * HDIM + d] = f2bf(vals[r]);
                } else {
                    ushort4 pk;
                    pk.x = f2bf(vals[0]); pk.y = f2bf(vals[1]);
                    pk.z = f2bf(vals[2]); pk.w = f2bf(vals[3]);
                    *(ushort4*)&vb[((size_t)bh * HDIM + d) * SEQ + ts] = pk;
                }
            }
        }
    }
}

// -------- W1 GEMM v2: 256x256 tile, BK=64, 8 waves, counted-vmcnt pipeline -----
// C[4096,4096] = A[4096,1024] @ Bt[4096,1024]^T, gelu->bf16.
// Why: the 2-barrier 128-tile structure is latency-bound at its ceiling (55us,
// MfmaUtil 24%): one slab's compute (~500cyc) < HBM latency (~900cyc), so the
// per-step vmcnt(0) drain always stalls (depth-3 failed for the same reason).
// Here one slab = 64 MFMA/wave (~2000cyc wall) >> HBM latency, and vmcnt(8)
// waits only on loads issued a full slab-compute earlier (T4: counted, never
// drain-0 mid-loop). 4x more MFMA per barrier. LDS 128KB dbuf -> 1 block/CU,
// 8 waves (2M x 4N, wave tile 128x64). Staging/swizzle identical to the proven
// CPR=8 path (0 bank conflicts). Buffer overwrite gated by lgkm(0)+barrier.
__global__ __launch_bounds__(512) void gemm256_gelu(
    const u16* __restrict__ A, const u16* __restrict__ Bt,
    const float* __restrict__ bias, u16* __restrict__ Cb)
{
    constexpr int BK  = 64;
    constexpr int ASZ = 256 * BK * 2;          // 32KB per A buffer
    constexpr int BSZ = 256 * BK * 2;          // 32KB per B buffer
    __shared__ __align__(16) char smem[2 * (ASZ + BSZ)];   // 128KB

    int t = threadIdx.x;
    int lane = t & 63, w = t >> 6;
    int wm = w >> 2, wn = w & 3;               // 2M x 4N wave grid
    int lr = lane & 15, lq = lane >> 4;
    // XCD remap (gridDim 16x16): all N-tiles of an M-row on one XCD
    int gx = gridDim.x;
    int lin = blockIdx.x + gx * blockIdx.y;
    int li = lin >> 3;
    int qy = li / gx;
    int ty = (lin & 7) * (gridDim.y >> 3) + qy;
    int tx = li - qy * gx;
    int m0 = ty * 256, n0 = tx * 256;
    int pg = (lq ^ (lr & 7)) * 16;

    // staging: 4 A-chunks + 4 B-chunks per thread per slab (2048 chunks/512thr)
    const u16* ap[4];
    const u16* bp[4];
#pragma unroll
    for (int i = 0; i < 4; i++) {
        int c = t + 512 * i, r = c >> 3, s = c & 7;
        int g = s ^ (r & 7);
        ap[i] = A  + (size_t)(m0 + r) * TD + g * 8;
        bp[i] = Bt + (size_t)(n0 + r) * TD + g * 8;
    }

    f32x4 acc[8][4];
#pragma unroll
    for (int i = 0; i < 8; i++)
#pragma unroll
        for (int j = 0; j < 4; j++) acc[i][j] = (f32x4){0.f, 0.f, 0.f, 0.f};

    // prologue: stage slabs 0 and 1 (16 loads/thread in flight)
#pragma unroll
    for (int s = 0; s < 2; s++) {
        char* Ab = smem + s * ASZ;
        char* Bb = smem + 2 * ASZ + s * BSZ;
#pragma unroll
        for (int i = 0; i < 4; i++) {
            async16(Ab + (t + 512 * i) * 16, ap[i]);
            ap[i] += BK;
        }
#pragma unroll
        for (int i = 0; i < 4; i++) {
            async16(Bb + (t + 512 * i) * 16, bp[i]);
            bp[i] += BK;
        }
    }

    constexpr int nk = TD / BK;                // 16 slabs
    for (int kt = 0; kt < nk; kt++) {
        int cur = kt & 1;
        if (kt + 1 < nk) asm volatile("s_waitcnt vmcnt(8)" ::: "memory");
        else             asm volatile("s_waitcnt vmcnt(0)" ::: "memory");
        __builtin_amdgcn_sched_barrier(0);
        __builtin_amdgcn_s_barrier();          // slab kt visible to all waves
        __builtin_amdgcn_sched_barrier(0);
        const char* Ac = smem + cur * ASZ;
        const char* Bc = smem + 2 * ASZ + cur * BSZ;
        __builtin_amdgcn_s_setprio(1);
#pragma unroll
        for (int h = 0; h < 2; h++) {
            bf16x8 af[8], bfr[4];
#pragma unroll
            for (int i = 0; i < 8; i++)
                af[i] = *(const bf16x8*)(Ac + (wm * 128 + i * 16 + lr) * 128 + (pg ^ (h * 64)));
#pragma unroll
            for (int j = 0; j < 4; j++)
                bfr[j] = *(const bf16x8*)(Bc + (wn * 64 + j * 16 + lr) * 128 + (pg ^ (h * 64)));
#pragma unroll
            for (int i = 0; i < 8; i++)
#pragma unroll
                for (int j = 0; j < 4; j++)
                    acc[i][j] = __builtin_amdgcn_mfma_f32_16x16x32_bf16(af[i], bfr[j], acc[i][j], 0, 0, 0);
        }
        __builtin_amdgcn_s_setprio(0);
        // my ds_reads done (frags in regs) -> all waves past -> safe to overwrite
        asm volatile("s_waitcnt lgkmcnt(0)" ::: "memory");
        __builtin_amdgcn_sched_barrier(0);
        __builtin_amdgcn_s_barrier();
        __builtin_amdgcn_sched_barrier(0);
        if (kt + 2 < nk) {                     // stage slab kt+2 into freed buffer
            char* An = smem + cur * ASZ;
            char* Bn = smem + 2 * ASZ + cur * BSZ;
#pragma unroll
            for (int i = 0; i < 4; i++) {
                async16(An + (t + 512 * i) * 16, ap[i]);
                ap[i] += BK;
            }
#pragma unroll
            for (int i = 0; i < 4; i++) {
                async16(Bn + (t + 512 * i) * 16, bp[i]);
                bp[i] += BK;
            }
        }
    }

    // epilogue: bias + gelu -> bf16
#pragma unroll
    for (int i = 0; i < 8; i++) {
        int rowb = m0 + wm * 128 + i * 16 + lq * 4;
#pragma unroll
        for (int j = 0; j < 4; j++) {
            int col = n0 + wn * 64 + j * 16 + lr;
            float bs = bias[col];
#pragma unroll
            for (int r = 0; r < 4; r++)
                Cb[(size_t)(rowb + r) * FFD + col] = f2bf(gelu_f(acc[i][j][r] + bs));
        }
    }
}

// ---------------- flash attention v4: one q-tile per block, CU-balanced remap --
__global__ __launch_bounds__(256, 4) void attn_mfma(const u16* __restrict__ qb,
                                                    const u16* __restrict__ kb,
                                                    const u16* __restrict__ vb,
                                                    u16* __restrict__ ctx)
{
    __shared__ __align__(16) char smem[40960];
    char* QP = smem;                        // 8KB Q tile / P buffer (wave-private rows)
    int lin = blockIdx.x + 32 * blockIdx.y;
    int xcd = lin & 7, idx = lin >> 3;      // idx 0..127 within XCD
    int u = idx & 31, v = idx >> 5;         // u: CU slot, v: round
    int bh = xcd + 8 * v;
    int qt = (v & 1) ? u : 31 - u;
    int bb = bh >> 4, h = bh & 15;
    int t = threadIdx.x, lane = t & 63, w = t >> 6;
    int lr = lane & 15, lq = lane >> 4;
    int sw = (lr & 7) * 16;                 // read-side swizzle
    int cA = (lq * 16) ^ sw;                // chunk lq   (k-half 0)
    int cB = (64 | (lq * 16)) ^ sw;         // chunk 4+lq (k-half 1)
    int c0 = t,        r0 = c0 >> 3, g0 = (c0 & 7) ^ (r0 & 7);
    int c1 = t + 256,  r1 = c1 >> 3, g1 = (c1 & 7) ^ (r1 & 7);
    size_t off0  = (size_t)r0 * 128  + g0 * 16;   // Q/K tiles: 128B per row
    size_t off1  = (size_t)r1 * 128  + g1 * 16;
    size_t voff0 = (size_t)r0 * 4096 + g0 * 16;   // V: row=d, global stride 4096B
    size_t voff1 = (size_t)r1 * 4096 + g1 * 16;

    const char* qg_base = (const char*)qb + (size_t)bh * SEQ * 128;
    const char* kg_base = (const char*)kb + (size_t)bh * SEQ * 128;
    const char* vg_base = (const char*)vb + (size_t)bh * 64 * 4096;

    const char* qg = qg_base + (size_t)qt * 8192;
    async16(QP + c0 * 16, qg + off0);
    async16(QP + c1 * 16, qg + off1);
    async16(smem + 8192 + c0 * 16, kg_base + off0);
    async16(smem + 8192 + c1 * 16, kg_base + off1);
    async16(smem + 24576 + c0 * 16, vg_base + voff0);
    async16(smem + 24576 + c1 * 16, vg_base + voff1);

    float mold = -INFINITY, lsum = 0.f;
    f32x4 o[4];
#pragma unroll
    for (int dj = 0; dj < 4; dj++) o[dj] = (f32x4){0.f, 0.f, 0.f, 0.f};
    bf16x8 bq0, bq1;

    for (int kt = 0; kt <= qt; ++kt) {
        int cur = kt & 1;
        __syncthreads();                // tile kt ready; other buf free
        if (kt < qt) {                  // prefetch kt+1 (drained at next barrier)
            const char* kgn = kg_base + (size_t)(kt + 1) * 8192;
            const char* vgn = vg_base + (size_t)(kt + 1) * 128;
            char* Kn = smem + 8192  + (1 - cur) * 8192;
            char* Vn = smem + 24576 + (1 - cur) * 8192;
            async16(Kn + c0 * 16, kgn + off0);
            async16(Kn + c1 * 16, kgn + off1);
            async16(Vn + c0 * 16, vgn + voff0);
            async16(Vn + c1 * 16, vgn + voff1);
        }
        if (kt == 0) {                  // Q frags -> regs (QP then reused as P)
            const char* qr = QP + (w * 16 + lr) * 128;
            bq0 = *(const bf16x8*)(qr + cA);
            bq1 = *(const bf16x8*)(qr + cB);
        }
        const char* Kc = smem + 8192  + cur * 8192;
        const char* Vc = smem + 24576 + cur * 8192;

        // S^T = K Q^T : lane holds keys j*16+lq*4+r (rows), q = w*16+lr (col)
        float sv[4][4];
        bool diag = (kt == qt);
        __builtin_amdgcn_s_setprio(1);
#pragma unroll
        for (int j = 0; j < 4; ++j) {
            const char* kr = Kc + (j * 16 + lr) * 128;
            bf16x8 ak0 = *(const bf16x8*)(kr + cA);
            bf16x8 ak1 = *(const bf16x8*)(kr + cB);
            f32x4 z = (f32x4){0.f, 0.f, 0.f, 0.f};
            z = __builtin_amdgcn_mfma_f32_16x16x32_bf16(ak0, bq0, z, 0, 0, 0);
            z = __builtin_amdgcn_mfma_f32_16x16x32_bf16(ak1, bq1, z, 0, 0, 0);
#pragma unroll
            for (int r = 0; r < 4; r++) {
                float xv = z[r];
                if (diag && (j * 16 + lq * 4 + r > w * 16 + lr)) xv = -INFINITY;
                sv[j][r] = xv;
            }
        }
        __builtin_amdgcn_s_setprio(0);
        // online softmax in exp2 domain; one q per lane
        float mx = sv[0][0];
#pragma unroll
        for (int j = 0; j < 4; j++)
#pragma unroll
            for (int r = 0; r < 4; r++) mx = fmaxf(mx, sv[j][r]);
        mx = fmaxf(mx, __shfl_xor(mx, 16));
        mx = fmaxf(mx, __shfl_xor(mx, 32));
        float mnew = fmaxf(mold, mx);
        float alpha = exp2f(mold - mnew);
        float rs = 0.f;
        unsigned pk[4][2];
#pragma unroll
        for (int j = 0; j < 4; j++)
#pragma unroll
            for (int hh = 0; hh < 2; hh++) {
                float p0 = exp2f(sv[j][2 * hh]     - mnew);
                float p1 = exp2f(sv[j][2 * hh + 1] - mnew);
                rs += p0 + p1;
                union { float f; unsigned u; } a0, a1;
                a0.f = p0; a1.f = p1;
                // truncation-pack: D = {hi16(p1), hi16(p0)} in ONE v_perm_b32
                pk[j][hh] = __builtin_amdgcn_perm(a1.u, a0.u, 0x07060302u);
            }
        rs += __shfl_xor(rs, 16);
        rs += __shfl_xor(rs, 32);
        lsum = lsum * alpha + rs;
        mold = mnew;
#pragma unroll
        for (int dj = 0; dj < 4; dj++)
#pragma unroll
            for (int r = 0; r < 4; r++) o[dj][r] *= alpha;

        // P^T -> LDS (wave-private rows; no barrier): row q=w*16+lr, b64 writes
        {
            char* pw = QP + (w * 16 + lr) * 128 + (lq & 1) * 8;
#pragma unroll
            for (int j = 0; j < 4; j++) {
                int pos = ((j * 2 + (lq >> 1)) * 16) ^ sw;
                uint2 u2; u2.x = pk[j][0]; u2.y = pk[j][1];
                *(uint2*)(pw + pos) = u2;
            }
        }
        asm volatile("s_waitcnt lgkmcnt(0)" ::: "memory");
        const char* pr = QP + (w * 16 + lr) * 128;
        bf16x8 bp0 = *(const bf16x8*)(pr + cA);
        bf16x8 bp1 = *(const bf16x8*)(pr + cB);
        // O^T += V^T P^T : rows d, cols q
        __builtin_amdgcn_s_setprio(1);
#pragma unroll
        for (int dj = 0; dj < 4; ++dj) {
            const char* vr = Vc + (dj * 16 + lr) * 128;
            bf16x8 av0 = *(const bf16x8*)(vr + cA);
            bf16x8 av1 = *(const bf16x8*)(vr + cB);
            o[dj] = __builtin_amdgcn_mfma_f32_16x16x32_bf16(av0, bp0, o[dj], 0, 0, 0);
            o[dj] = __builtin_amdgcn_mfma_f32_16x16x32_bf16(av1, bp1, o[dj], 0, 0, 0);
        }
        __builtin_amdgcn_s_setprio(0);
    }

    float inv = 1.f / lsum;
    int tok = qt * 64 + w * 16 + lr;
    u16* cp = ctx + ((size_t)(bb * SEQ) + tok) * TD + h * HDIM + lq * 4;
#pragma unroll
    for (int dj = 0; dj < 4; dj++) {
        ushort4 s4;
        s4.x = f2bf(o[dj][0] * inv); s4.y = f2bf(o[dj][1] * inv);
        s4.z = f2bf(o[dj][2] * inv); s4.w = f2bf(o[dj][3] * inv);
        *(ushort4*)(cp + dj * 16) = s4;
    }
}

extern "C" void kernel_launch(void* const* d_in, const int* in_sizes, int n_in,
                              void* d_out, int out_size, void* d_ws, size_t ws_size,
                              hipStream_t stream)
{
    const float* x    = (const float*)d_in[0];
    const float* g1   = (const float*)d_in[1];
    const float* b1   = (const float*)d_in[2];
    const float* Wqkv = (const float*)d_in[3];
    const float* bqkv = (const float*)d_in[4];
    const float* Wo   = (const float*)d_in[5];
    const float* bo   = (const float*)d_in[6];
    const float* g2   = (const float*)d_in[7];
    const float* b2   = (const float*)d_in[8];
    const float* W1   = (const float*)d_in[9];
    const float* b1f  = (const float*)d_in[10];
    const float* W2   = (const float*)d_in[11];
    const float* b2f  = (const float*)d_in[12];
    float* out = (float*)d_out;

    char* ws = (char*)d_ws;
    const size_t MB = 1ull << 20;
    u16* wqkvT = (u16*)(ws + 0 * MB);    // 6 MB  [3072][1024]
    u16* woT   = (u16*)(ws + 6 * MB);    // 2 MB  [1024][1024]
    u16* w1T   = (u16*)(ws + 8 * MB);    // 8 MB  [4096][1024]
    u16* w2T   = (u16*)(ws + 16 * MB);   // 8 MB  [1024][4096]
    u16* qbuf  = (u16*)(ws + 24 * MB);   // 8 MB  [32][2048][64] (pre-scaled)
    u16* kbuf  = (u16*)(ws + 32 * MB);   // 8 MB
    u16* vbuf  = (u16*)(ws + 40 * MB);   // 8 MB  [32][64][2048]
    u16* hbuf  = (u16*)(ws + 48 * MB);   // 8 MB  h then hh
    u16* ctx   = (u16*)(ws + 56 * MB);   // 8 MB
    float* x2  = (float*)(ws + 64 * MB); // 16 MB
    u16* ff1   = (u16*)(ws + 80 * MB);   // 32 MB  -> 112 MB total

    // fused: weight transposes + LN1 (independent work, one dispatch)
    prep_kernel<<<3072 + NROWS, 256, 0, stream>>>(
        Wqkv, Wo, W1, W2, wqkvT, woT, w1T, w2T, x, g1, b1, hbuf);

    gemm_mfma<EPI_QKV, 128, 64><<<dim3(3 * TD / 128, NROWS / 128), 256, 0, stream>>>(
        NROWS, 3 * TD, TD, hbuf, wqkvT, bqkv, nullptr, nullptr, nullptr, qbuf, kbuf, vbuf);
    attn_mfma<<<dim3(32, NB * NH), 256, 0, stream>>>(qbuf, kbuf, vbuf, ctx);
    gemm_mfma<EPI_F32RES, 64, 64><<<dim3(TD / 64, NROWS / 128), 256, 0, stream>>>(
        NROWS, TD, TD, ctx, woT, bo, x, x2, nullptr, nullptr, nullptr, nullptr);
    ln_bf16<<<NROWS, 256, 0, stream>>>(x2, g2, b2, hbuf);
    // W1: 256x256/8-wave counted-vmcnt kernel (structural test vs 55.1us ceiling)
    gemm256_gelu<<<dim3(FFD / 256, NROWS / 256), 512, 0, stream>>>(hbuf, w1T, b1f, ff1);
    gemm_mfma<EPI_F32RES, 64, 64><<<dim3(TD / 64, NROWS / 128), 256, 0, stream>>>(
        NROWS, TD, FFD, ff1, w2T, b2f, x2, out, nullptr, nullptr, nullptr, nullptr);
}

// Round 20
// 317.611 us; speedup vs baseline: 1.0222x; 1.0082x over previous
//
#include <hip/hip_runtime.h>
#include <math.h>

#define TD 1024      // model dim
#define NH 16        // heads
#define HDIM 64      // head dim
#define SEQ 2048     // seq len
#define NB 2         // batch
#define NROWS 4096   // NB*SEQ
#define FFD 4096     // ffn dim

// 1/sqrt(64) * log2(e): softmax computed in exp2 domain; folded into Q at QKV epilogue
#define QSCALE 0.18033688011112042f

typedef unsigned short u16;
typedef __attribute__((ext_vector_type(8))) short bf16x8;   // 8 bf16 = 4 VGPR
typedef __attribute__((ext_vector_type(4))) float f32x4;    // MFMA acc

__device__ __forceinline__ u16 f2bf(float f) {
    union { float f; unsigned u; } v; v.f = f;
    return (u16)((v.u + 0x7FFFu + ((v.u >> 16) & 1u)) >> 16);
}

// async global->LDS, 16B per lane. LDS dest must be wave-uniform base + lane*16.
__device__ __forceinline__ void async16(void* lds, const void* g) {
    __builtin_amdgcn_global_load_lds(
        (const __attribute__((address_space(1))) unsigned*)g,
        (__attribute__((address_space(3))) unsigned*)lds, 16, 0, 0);
}

// tanh-form GELU (max |err| vs exact erf-GELU ~3e-3; threshold headroom 4x)
__device__ __forceinline__ float gelu_f(float v) {
    float u = 0.7978845608028654f * (v + 0.044715f * v * v * v);
    float e = __expf(2.f * u);
    float th = 1.f - 2.f * __builtin_amdgcn_rcpf(e + 1.f);
    return 0.5f * v * (1.f + th);
}

// ---------------- LayerNorm -> bf16 out: one block per row of 1024 -------------
__global__ __launch_bounds__(256) void ln_bf16(const float* __restrict__ x,
                                               const float* __restrict__ g,
                                               const float* __restrict__ b,
                                               u16* __restrict__ out)
{
    int row = blockIdx.x;
    const float* xr = x + (size_t)row * TD;
    u16* outr = out + (size_t)row * TD;
    int t = threadIdx.x;
    float v[4];
    float s = 0.f, ss = 0.f;
#pragma unroll
    for (int i = 0; i < 4; i++) {
        v[i] = xr[t + 256 * i];
        s += v[i];
        ss += v[i] * v[i];
    }
#pragma unroll
    for (int o = 32; o > 0; o >>= 1) {
        s  += __shfl_down(s, o);
        ss += __shfl_down(ss, o);
    }
    __shared__ float sm[4], sm2[4];
    int wave = t >> 6, lane = t & 63;
    if (lane == 0) { sm[wave] = s; sm2[wave] = ss; }
    __syncthreads();
    s  = sm[0] + sm[1] + sm[2] + sm[3];
    ss = sm2[0] + sm2[1] + sm2[2] + sm2[3];
    float mu  = s * (1.f / TD);
    float var = ss * (1.f / TD) - mu * mu;
    float rstd = rsqrtf(var + 1e-5f);
#pragma unroll
    for (int i = 0; i < 4; i++) {
        int c = t + 256 * i;
        outr[c] = f2bf((v[i] - mu) * rstd * g[c] + b[c]);
    }
}

// --- prep: fused weight convert+transpose (blocks 0..3071) + LN1 (3072..7167) --
__global__ __launch_bounds__(256) void prep_kernel(
    const float* __restrict__ Wqkv, const float* __restrict__ Wo,
    const float* __restrict__ W1,   const float* __restrict__ W2,
    u16* __restrict__ wqkvT, u16* __restrict__ woT,
    u16* __restrict__ w1T,   u16* __restrict__ w2T,
    const float* __restrict__ x, const float* __restrict__ g1,
    const float* __restrict__ b1, u16* __restrict__ hbuf)
{
    int blk = blockIdx.x;
    int t = threadIdx.x;
    if (blk >= 3072) {               // ---- LN1 path ----
        int row = blk - 3072;
        const float* xr = x + (size_t)row * TD;
        u16* outr = hbuf + (size_t)row * TD;
        float v[4];
        float s = 0.f, ss = 0.f;
#pragma unroll
        for (int i = 0; i < 4; i++) {
            v[i] = xr[t + 256 * i];
            s += v[i];
            ss += v[i] * v[i];
        }
#pragma unroll
        for (int o = 32; o > 0; o >>= 1) {
            s  += __shfl_down(s, o);
            ss += __shfl_down(ss, o);
        }
        __shared__ float sm[4], sm2[4];
        int wave = t >> 6, lane = t & 63;
        if (lane == 0) { sm[wave] = s; sm2[wave] = ss; }
        __syncthreads();
        s  = sm[0] + sm[1] + sm[2] + sm[3];
        ss = sm2[0] + sm2[1] + sm2[2] + sm2[3];
        float mu  = s * (1.f / TD);
        float var = ss * (1.f / TD) - mu * mu;
        float rstd = rsqrtf(var + 1e-5f);
#pragma unroll
        for (int i = 0; i < 4; i++) {
            int c = t + 256 * i;
            outr[c] = f2bf((v[i] - mu) * rstd * g1[c] + b1[c]);
        }
        return;
    }
    // ---- weight transpose path ----
    const float* W; u16* Wt; int K, N, local, nx;
    if (blk < 768)       { W = Wqkv; Wt = wqkvT; K = TD;  N = 3 * TD; local = blk;        nx = 48; }
    else if (blk < 1024) { W = Wo;   Wt = woT;   K = TD;  N = TD;     local = blk - 768;  nx = 16; }
    else if (blk < 2048) { W = W1;   Wt = w1T;   K = TD;  N = FFD;    local = blk - 1024; nx = 64; }
    else                 { W = W2;   Wt = w2T;   K = FFD; N = TD;     local = blk - 2048; nx = 16; }
    int n0 = (local % nx) * 64, k0 = (local / nx) * 64;
    __shared__ u16 tile[64][65];
    int c = t & 63, rq = t >> 6;
#pragma unroll
    for (int i = 0; i < 16; i++) {
        int r = rq * 16 + i;
        tile[r][c] = f2bf(W[(size_t)(k0 + r) * N + n0 + c]);
    }
    __syncthreads();
#pragma unroll
    for (int i = 0; i < 16; i++) {
        int r = rq * 16 + i;
        Wt[(size_t)(n0 + r) * K + k0 + c] = tile[c][r];
    }
}

// ---------------- bf16 MFMA GEMM: 128xTN tile, BK k-slab, dbuf LDS -------------
// (legacy 2-barrier structure; measured ceiling W1=55.1us. Kept for QKV/Wo/W2.)
#define EPI_QKV 0
#define EPI_F32RES 1
#define EPI_GELU 2

template<int EPI, int TN, int BK>
__global__ __launch_bounds__(256) void gemm_mfma(int M, int N, int K,
    const u16* __restrict__ A, const u16* __restrict__ Bt,
    const float* __restrict__ bias, const float* __restrict__ res,
    float* __restrict__ Cf, u16* __restrict__ Cb,
    u16* __restrict__ qb, u16* __restrict__ kb, u16* __restrict__ vb)
{
    constexpr int WN  = TN / 2;               // per-wave N extent (2 waves along N)
    constexpr int NJ  = WN / 16;              // B frags per wave
    constexpr int KH  = BK / 32;              // 32-elem k-halves per slab
    constexpr int CPR = BK / 8;               // 16B chunks per tile-row
    constexpr int ACH = (128 * CPR) / 256;    // A chunks per thread
    constexpr int BCH = (TN  * CPR) / 256;    // B chunks per thread
    constexpr int ASZ = 128 * BK * 2;         // bytes per A buffer
    constexpr int BSZ = TN  * BK * 2;
    __shared__ __align__(16) char smem[2 * (ASZ + BSZ)];

    int t = threadIdx.x;
    int lane = t & 63, w = t >> 6;
    int wm = w >> 1, wn = w & 1;              // 2x2 wave grid: wave = 64(M) x WN(N)
    int lr = lane & 15, lq = lane >> 4;
    int gx = gridDim.x;
    int lin = blockIdx.x + gx * blockIdx.y;
    int li = lin >> 3;
    int qy = li / gx;
    int ty = (lin & 7) * (gridDim.y >> 3) + qy;
    int tx = li - qy * gx;
    int m0 = ty * 128, n0 = tx * TN;
    int pg = (lq ^ (lr & (CPR - 1))) * 16;    // swizzled frag-read granule offset

    const u16* ap[ACH];
    const u16* bp[BCH];
#pragma unroll
    for (int i = 0; i < ACH; i++) {
        int c = t + 256 * i, r = c / CPR, s = c % CPR;
        int g = s ^ (r & (CPR - 1));
        ap[i] = A + (size_t)(m0 + r) * K + g * 8;
    }
#pragma unroll
    for (int i = 0; i < BCH; i++) {
        int c = t + 256 * i, r = c / CPR, s = c % CPR;
        int g = s ^ (r & (CPR - 1));
        bp[i] = Bt + (size_t)(n0 + r) * K + g * 8;
    }

    f32x4 acc[4][NJ];
#pragma unroll
    for (int i = 0; i < 4; i++)
#pragma unroll
        for (int j = 0; j < NJ; j++) acc[i][j] = (f32x4){0.f, 0.f, 0.f, 0.f};

#pragma unroll
    for (int i = 0; i < ACH; i++)
        async16(smem + (t + 256 * i) * 16, ap[i]);
#pragma unroll
    for (int i = 0; i < BCH; i++)
        async16(smem + 2 * ASZ + (t + 256 * i) * 16, bp[i]);

    int nk = K / BK;
    for (int kt = 0; kt < nk; kt++) {
        int cur = kt & 1;
        __syncthreads();
        if (kt + 1 < nk) {
            char* An = smem + (1 - cur) * ASZ;
            char* Bn = smem + 2 * ASZ + (1 - cur) * BSZ;
#pragma unroll
            for (int i = 0; i < ACH; i++) {
                ap[i] += BK;
                async16(An + (t + 256 * i) * 16, ap[i]);
            }
#pragma unroll
            for (int i = 0; i < BCH; i++) {
                bp[i] += BK;
                async16(Bn + (t + 256 * i) * 16, bp[i]);
            }
        }
        const char* Ac = smem + cur * ASZ;
        const char* Bc = smem + 2 * ASZ + cur * BSZ;
#pragma unroll
        for (int h = 0; h < KH; h++) {
            bf16x8 af[4], bfr[NJ];
#pragma unroll
            for (int i = 0; i < 4; i++)
                af[i] = *(const bf16x8*)(Ac + (wm * 64 + i * 16 + lr) * (2 * BK) + (pg ^ (h * 64)));
#pragma unroll
            for (int j = 0; j < NJ; j++)
                bfr[j] = *(const bf16x8*)(Bc + (wn * WN + j * 16 + lr) * (2 * BK) + (pg ^ (h * 64)));
#pragma unroll
            for (int i = 0; i < 4; i++)
#pragma unroll
                for (int j = 0; j < NJ; j++)
                    acc[i][j] = __builtin_amdgcn_mfma_f32_16x16x32_bf16(af[i], bfr[j], acc[i][j], 0, 0, 0);
        }
    }

#pragma unroll
    for (int i = 0; i < 4; i++) {
        int rowb = m0 + wm * 64 + i * 16 + lq * 4;
#pragma unroll
        for (int j = 0; j < NJ; j++) {
            int col = n0 + wn * WN + j * 16 + lr;
            float bs = bias[col];
            float vals[4];
#pragma unroll
            for (int r = 0; r < 4; r++) vals[r] = acc[i][j][r] + bs;
            if (EPI == EPI_F32RES) {
#pragma unroll
                for (int r = 0; r < 4; r++) {
                    int rr = rowb + r;
                    Cf[(size_t)rr * N + col] = vals[r] + res[(size_t)rr * N + col];
                }
            } else if (EPI == EPI_GELU) {
#pragma unroll
                for (int r = 0; r < 4; r++)
                    Cb[(size_t)(rowb + r) * N + col] = f2bf(gelu_f(vals[r]));
            } else { // QKV scatter: Q/K [bh][seq][64] (Q pre-scaled), V [bh][64][seq]
                int comp = col >> 10, cw = col & 1023;
                int h = cw >> 6, d = cw & 63;
                int bb0 = rowb >> 11, ts = rowb & 2047;   // rowb%4==0: no batch crossing
                int bh = bb0 * NH + h;
                if (comp == 0) {
#pragma unroll
                    for (int r = 0; r < 4; r++)
                        qb[((size_t)bh * SEQ + ts + r) * HDIM + d] = f2bf(vals[r] * QSCALE);
                } else if (comp == 1) {
#pragma unroll
                    for (int r = 0; r < 4; r++)
                        kb[((size_t)bh * SEQ + ts + r) * HDIM + d] = f2bf(vals[r]);
                } else {
                    ushort4 pk;
                    pk.x = f2bf(vals[0]); pk.y = f2bf(vals[1]);
                    pk.z = f2bf(vals[2]); pk.w = f2bf(vals[3]);
                    *(ushort4*)&vb[((size_t)bh * HDIM + d) * SEQ + ts] = pk;
                }
            }
        }
    }
}

// -------- W1 GEMM v2: 256x256 tile, BK=64, 8 waves, counted-vmcnt pipeline -----
// Measured R19: correct, W1 dropped below top-5 (<52.4us vs 55.1 prior). Kept.
__global__ __launch_bounds__(512) void gemm256_gelu(
    const u16* __restrict__ A, const u16* __restrict__ Bt,
    const float* __restrict__ bias, u16* __restrict__ Cb)
{
    constexpr int BK  = 64;
    constexpr int ASZ = 256 * BK * 2;          // 32KB per A buffer
    constexpr int BSZ = 256 * BK * 2;          // 32KB per B buffer
    __shared__ __align__(16) char smem[2 * (ASZ + BSZ)];   // 128KB

    int t = threadIdx.x;
    int lane = t & 63, w = t >> 6;
    int wm = w >> 2, wn = w & 3;               // 2M x 4N wave grid
    int lr = lane & 15, lq = lane >> 4;
    int gx = gridDim.x;
    int lin = blockIdx.x + gx * blockIdx.y;
    int li = lin >> 3;
    int qy = li / gx;
    int ty = (lin & 7) * (gridDim.y >> 3) + qy;
    int tx = li - qy * gx;
    int m0 = ty * 256, n0 = tx * 256;
    int pg = (lq ^ (lr & 7)) * 16;

    const u16* ap[4];
    const u16* bp[4];
#pragma unroll
    for (int i = 0; i < 4; i++) {
        int c = t + 512 * i, r = c >> 3, s = c & 7;
        int g = s ^ (r & 7);
        ap[i] = A  + (size_t)(m0 + r) * TD + g * 8;
        bp[i] = Bt + (size_t)(n0 + r) * TD + g * 8;
    }

    f32x4 acc[8][4];
#pragma unroll
    for (int i = 0; i < 8; i++)
#pragma unroll
        for (int j = 0; j < 4; j++) acc[i][j] = (f32x4){0.f, 0.f, 0.f, 0.f};

#pragma unroll
    for (int s = 0; s < 2; s++) {
        char* Ab = smem + s * ASZ;
        char* Bb = smem + 2 * ASZ + s * BSZ;
#pragma unroll
        for (int i = 0; i < 4; i++) {
            async16(Ab + (t + 512 * i) * 16, ap[i]);
            ap[i] += BK;
        }
#pragma unroll
        for (int i = 0; i < 4; i++) {
            async16(Bb + (t + 512 * i) * 16, bp[i]);
            bp[i] += BK;
        }
    }

    constexpr int nk = TD / BK;                // 16 slabs
    for (int kt = 0; kt < nk; kt++) {
        int cur = kt & 1;
        if (kt + 1 < nk) asm volatile("s_waitcnt vmcnt(8)" ::: "memory");
        else             asm volatile("s_waitcnt vmcnt(0)" ::: "memory");
        __builtin_amdgcn_sched_barrier(0);
        __builtin_amdgcn_s_barrier();          // slab kt visible to all waves
        __builtin_amdgcn_sched_barrier(0);
        const char* Ac = smem + cur * ASZ;
        const char* Bc = smem + 2 * ASZ + cur * BSZ;
        __builtin_amdgcn_s_setprio(1);
#pragma unroll
        for (int h = 0; h < 2; h++) {
            bf16x8 af[8], bfr[4];
#pragma unroll
            for (int i = 0; i < 8; i++)
                af[i] = *(const bf16x8*)(Ac + (wm * 128 + i * 16 + lr) * 128 + (pg ^ (h * 64)));
#pragma unroll
            for (int j = 0; j < 4; j++)
                bfr[j] = *(const bf16x8*)(Bc + (wn * 64 + j * 16 + lr) * 128 + (pg ^ (h * 64)));
#pragma unroll
            for (int i = 0; i < 8; i++)
#pragma unroll
                for (int j = 0; j < 4; j++)
                    acc[i][j] = __builtin_amdgcn_mfma_f32_16x16x32_bf16(af[i], bfr[j], acc[i][j], 0, 0, 0);
        }
        __builtin_amdgcn_s_setprio(0);
        asm volatile("s_waitcnt lgkmcnt(0)" ::: "memory");
        __builtin_amdgcn_sched_barrier(0);
        __builtin_amdgcn_s_barrier();
        __builtin_amdgcn_sched_barrier(0);
        if (kt + 2 < nk) {                     // stage slab kt+2 into freed buffer
            char* An = smem + cur * ASZ;
            char* Bn = smem + 2 * ASZ + cur * BSZ;
#pragma unroll
            for (int i = 0; i < 4; i++) {
                async16(An + (t + 512 * i) * 16, ap[i]);
                ap[i] += BK;
            }
#pragma unroll
            for (int i = 0; i < 4; i++) {
                async16(Bn + (t + 512 * i) * 16, bp[i]);
                bp[i] += BK;
            }
        }
    }

#pragma unroll
    for (int i = 0; i < 8; i++) {
        int rowb = m0 + wm * 128 + i * 16 + lq * 4;
#pragma unroll
        for (int j = 0; j < 4; j++) {
            int col = n0 + wn * 64 + j * 16 + lr;
            float bs = bias[col];
#pragma unroll
            for (int r = 0; r < 4; r++)
                Cb[(size_t)(rowb + r) * FFD + col] = f2bf(gelu_f(acc[i][j][r] + bs));
        }
    }
}

// ---------------- flash attention v5: v4 + defer-max (T13) + max-tree ----------
// Measured v4: 52.5us, VALUBusy 45%, MfmaUtil 12.5% -> softmax VALU chain is the
// largest consumer. defer-max: skip O/lsum rescale while __all(pmax-m <= 8)
// (P bounded by 2^8, bf16-safe; catalog m214v23 +5%, data-independent).
// Wave-uniform branch via __all -> no divergence. fmax reduce as 4-deep tree.
__global__ __launch_bounds__(256, 4) void attn_mfma(const u16* __restrict__ qb,
                                                    const u16* __restrict__ kb,
                                                    const u16* __restrict__ vb,
                                                    u16* __restrict__ ctx)
{
    __shared__ __align__(16) char smem[40960];
    char* QP = smem;                        // 8KB Q tile / P buffer (wave-private rows)
    int lin = blockIdx.x + 32 * blockIdx.y;
    int xcd = lin & 7, idx = lin >> 3;      // idx 0..127 within XCD
    int u = idx & 31, v = idx >> 5;         // u: CU slot, v: round
    int bh = xcd + 8 * v;
    int qt = (v & 1) ? u : 31 - u;
    int bb = bh >> 4, h = bh & 15;
    int t = threadIdx.x, lane = t & 63, w = t >> 6;
    int lr = lane & 15, lq = lane >> 4;
    int sw = (lr & 7) * 16;                 // read-side swizzle
    int cA = (lq * 16) ^ sw;                // chunk lq   (k-half 0)
    int cB = (64 | (lq * 16)) ^ sw;         // chunk 4+lq (k-half 1)
    int c0 = t,        r0 = c0 >> 3, g0 = (c0 & 7) ^ (r0 & 7);
    int c1 = t + 256,  r1 = c1 >> 3, g1 = (c1 & 7) ^ (r1 & 7);
    size_t off0  = (size_t)r0 * 128  + g0 * 16;   // Q/K tiles: 128B per row
    size_t off1  = (size_t)r1 * 128  + g1 * 16;
    size_t voff0 = (size_t)r0 * 4096 + g0 * 16;   // V: row=d, global stride 4096B
    size_t voff1 = (size_t)r1 * 4096 + g1 * 16;

    const char* qg_base = (const char*)qb + (size_t)bh * SEQ * 128;
    const char* kg_base = (const char*)kb + (size_t)bh * SEQ * 128;
    const char* vg_base = (const char*)vb + (size_t)bh * 64 * 4096;

    const char* qg = qg_base + (size_t)qt * 8192;
    async16(QP + c0 * 16, qg + off0);
    async16(QP + c1 * 16, qg + off1);
    async16(smem + 8192 + c0 * 16, kg_base + off0);
    async16(smem + 8192 + c1 * 16, kg_base + off1);
    async16(smem + 24576 + c0 * 16, vg_base + voff0);
    async16(smem + 24576 + c1 * 16, vg_base + voff1);

    float mold = -INFINITY, lsum = 0.f;
    f32x4 o[4];
#pragma unroll
    for (int dj = 0; dj < 4; dj++) o[dj] = (f32x4){0.f, 0.f, 0.f, 0.f};
    bf16x8 bq0, bq1;

    for (int kt = 0; kt <= qt; ++kt) {
        int cur = kt & 1;
        __syncthreads();                // tile kt ready; other buf free
        if (kt < qt) {                  // prefetch kt+1 (drained at next barrier)
            const char* kgn = kg_base + (size_t)(kt + 1) * 8192;
            const char* vgn = vg_base + (size_t)(kt + 1) * 128;
            char* Kn = smem + 8192  + (1 - cur) * 8192;
            char* Vn = smem + 24576 + (1 - cur) * 8192;
            async16(Kn + c0 * 16, kgn + off0);
            async16(Kn + c1 * 16, kgn + off1);
            async16(Vn + c0 * 16, vgn + voff0);
            async16(Vn + c1 * 16, vgn + voff1);
        }
        if (kt == 0) {                  // Q frags -> regs (QP then reused as P)
            const char* qr = QP + (w * 16 + lr) * 128;
            bq0 = *(const bf16x8*)(qr + cA);
            bq1 = *(const bf16x8*)(qr + cB);
        }
        const char* Kc = smem + 8192  + cur * 8192;
        const char* Vc = smem + 24576 + cur * 8192;

        // S^T = K Q^T : lane holds keys j*16+lq*4+r (rows), q = w*16+lr (col)
        float sv[4][4];
        bool diag = (kt == qt);
        __builtin_amdgcn_s_setprio(1);
#pragma unroll
        for (int j = 0; j < 4; ++j) {
            const char* kr = Kc + (j * 16 + lr) * 128;
            bf16x8 ak0 = *(const bf16x8*)(kr + cA);
            bf16x8 ak1 = *(const bf16x8*)(kr + cB);
            f32x4 z = (f32x4){0.f, 0.f, 0.f, 0.f};
            z = __builtin_amdgcn_mfma_f32_16x16x32_bf16(ak0, bq0, z, 0, 0, 0);
            z = __builtin_amdgcn_mfma_f32_16x16x32_bf16(ak1, bq1, z, 0, 0, 0);
#pragma unroll
            for (int r = 0; r < 4; r++) {
                float xv = z[r];
                if (diag && (j * 16 + lq * 4 + r > w * 16 + lr)) xv = -INFINITY;
                sv[j][r] = xv;
            }
        }
        __builtin_amdgcn_s_setprio(0);
        // tile max: 4-deep pairwise tree (was 16-deep serial chain)
        float m0a = fmaxf(fmaxf(sv[0][0], sv[0][1]), fmaxf(sv[0][2], sv[0][3]));
        float m1a = fmaxf(fmaxf(sv[1][0], sv[1][1]), fmaxf(sv[1][2], sv[1][3]));
        float m2a = fmaxf(fmaxf(sv[2][0], sv[2][1]), fmaxf(sv[2][2], sv[2][3]));
        float m3a = fmaxf(fmaxf(sv[3][0], sv[3][1]), fmaxf(sv[3][2], sv[3][3]));
        float pmax = fmaxf(fmaxf(m0a, m1a), fmaxf(m2a, m3a));
        pmax = fmaxf(pmax, __shfl_xor(pmax, 16));
        pmax = fmaxf(pmax, __shfl_xor(pmax, 32));
        // defer-max: rescale only when running max grows by > 8 (wave-uniform)
        if (!__all(pmax - mold <= 8.f)) {
            float mnew = fmaxf(mold, pmax);
            float alpha = exp2f(mold - mnew);
            lsum *= alpha;
#pragma unroll
            for (int dj = 0; dj < 4; dj++)
#pragma unroll
                for (int r = 0; r < 4; r++) o[dj][r] *= alpha;
            mold = mnew;
        }
        float rs = 0.f;
        unsigned pk[4][2];
#pragma unroll
        for (int j = 0; j < 4; j++)
#pragma unroll
            for (int hh = 0; hh < 2; hh++) {
                float p0 = exp2f(sv[j][2 * hh]     - mold);
                float p1 = exp2f(sv[j][2 * hh + 1] - mold);
                rs += p0 + p1;
                union { float f; unsigned u; } a0, a1;
                a0.f = p0; a1.f = p1;
                // truncation-pack: D = {hi16(p1), hi16(p0)} in ONE v_perm_b32
                pk[j][hh] = __builtin_amdgcn_perm(a1.u, a0.u, 0x07060302u);
            }
        rs += __shfl_xor(rs, 16);
        rs += __shfl_xor(rs, 32);
        lsum += rs;

        // P^T -> LDS (wave-private rows; no barrier): row q=w*16+lr, b64 writes
        {
            char* pw = QP + (w * 16 + lr) * 128 + (lq & 1) * 8;
#pragma unroll
            for (int j = 0; j < 4; j++) {
                int pos = ((j * 2 + (lq >> 1)) * 16) ^ sw;
                uint2 u2; u2.x = pk[j][0]; u2.y = pk[j][1];
                *(uint2*)(pw + pos) = u2;
            }
        }
        asm volatile("s_waitcnt lgkmcnt(0)" ::: "memory");
        const char* pr = QP + (w * 16 + lr) * 128;
        bf16x8 bp0 = *(const bf16x8*)(pr + cA);
        bf16x8 bp1 = *(const bf16x8*)(pr + cB);
        // O^T += V^T P^T : rows d, cols q
        __builtin_amdgcn_s_setprio(1);
#pragma unroll
        for (int dj = 0; dj < 4; ++dj) {
            const char* vr = Vc + (dj * 16 + lr) * 128;
            bf16x8 av0 = *(const bf16x8*)(vr + cA);
            bf16x8 av1 = *(const bf16x8*)(vr + cB);
            o[dj] = __builtin_amdgcn_mfma_f32_16x16x32_bf16(av0, bp0, o[dj], 0, 0, 0);
            o[dj] = __builtin_amdgcn_mfma_f32_16x16x32_bf16(av1, bp1, o[dj], 0, 0, 0);
        }
        __builtin_amdgcn_s_setprio(0);
    }

    float inv = 1.f / lsum;
    int tok = qt * 64 + w * 16 + lr;
    u16* cp = ctx + ((size_t)(bb * SEQ) + tok) * TD + h * HDIM + lq * 4;
#pragma unroll
    for (int dj = 0; dj < 4; dj++) {
        ushort4 s4;
        s4.x = f2bf(o[dj][0] * inv); s4.y = f2bf(o[dj][1] * inv);
        s4.z = f2bf(o[dj][2] * inv); s4.w = f2bf(o[dj][3] * inv);
        *(ushort4*)(cp + dj * 16) = s4;
    }
}

extern "C" void kernel_launch(void* const* d_in, const int* in_sizes, int n_in,
                              void* d_out, int out_size, void* d_ws, size_t ws_size,
                              hipStream_t stream)
{
    const float* x    = (const float*)d_in[0];
    const float* g1   = (const float*)d_in[1];
    const float* b1   = (const float*)d_in[2];
    const float* Wqkv = (const float*)d_in[3];
    const float* bqkv = (const float*)d_in[4];
    const float* Wo   = (const float*)d_in[5];
    const float* bo   = (const float*)d_in[6];
    const float* g2   = (const float*)d_in[7];
    const float* b2   = (const float*)d_in[8];
    const float* W1   = (const float*)d_in[9];
    const float* b1f  = (const float*)d_in[10];
    const float* W2   = (const float*)d_in[11];
    const float* b2f  = (const float*)d_in[12];
    float* out = (float*)d_out;

    char* ws = (char*)d_ws;
    const size_t MB = 1ull << 20;
    u16* wqkvT = (u16*)(ws + 0 * MB);    // 6 MB  [3072][1024]
    u16* woT   = (u16*)(ws + 6 * MB);    // 2 MB  [1024][1024]
    u16* w1T   = (u16*)(ws + 8 * MB);    // 8 MB  [4096][1024]
    u16* w2T   = (u16*)(ws + 16 * MB);   // 8 MB  [1024][4096]
    u16* qbuf  = (u16*)(ws + 24 * MB);   // 8 MB  [32][2048][64] (pre-scaled)
    u16* kbuf  = (u16*)(ws + 32 * MB);   // 8 MB
    u16* vbuf  = (u16*)(ws + 40 * MB);   // 8 MB  [32][64][2048]
    u16* hbuf  = (u16*)(ws + 48 * MB);   // 8 MB  h then hh
    u16* ctx   = (u16*)(ws + 56 * MB);   // 8 MB
    float* x2  = (float*)(ws + 64 * MB); // 16 MB
    u16* ff1   = (u16*)(ws + 80 * MB);   // 32 MB  -> 112 MB total

    // fused: weight transposes + LN1 (independent work, one dispatch)
    prep_kernel<<<3072 + NROWS, 256, 0, stream>>>(
        Wqkv, Wo, W1, W2, wqkvT, woT, w1T, w2T, x, g1, b1, hbuf);

    gemm_mfma<EPI_QKV, 128, 64><<<dim3(3 * TD / 128, NROWS / 128), 256, 0, stream>>>(
        NROWS, 3 * TD, TD, hbuf, wqkvT, bqkv, nullptr, nullptr, nullptr, qbuf, kbuf, vbuf);
    attn_mfma<<<dim3(32, NB * NH), 256, 0, stream>>>(qbuf, kbuf, vbuf, ctx);
    gemm_mfma<EPI_F32RES, 64, 64><<<dim3(TD / 64, NROWS / 128), 256, 0, stream>>>(
        NROWS, TD, TD, ctx, woT, bo, x, x2, nullptr, nullptr, nullptr, nullptr);
    ln_bf16<<<NROWS, 256, 0, stream>>>(x2, g2, b2, hbuf);
    gemm256_gelu<<<dim3(FFD / 256, NROWS / 256), 512, 0, stream>>>(hbuf, w1T, b1f, ff1);
    gemm_mfma<EPI_F32RES, 64, 64><<<dim3(TD / 64, NROWS / 128), 256, 0, stream>>>(
        NROWS, TD, FFD, ff1, w2T, b2f, x2, out, nullptr, nullptr, nullptr, nullptr);
}

// Round 21
// 300.676 us; speedup vs baseline: 1.0797x; 1.0563x over previous
//
#include <hip/hip_runtime.h>
#include <math.h>

#define TD 1024      // model dim
#define NH 16        // heads
#define HDIM 64      // head dim
#define SEQ 2048     // seq len
#define NB 2         // batch
#define NROWS 4096   // NB*SEQ
#define FFD 4096     // ffn dim

// 1/sqrt(64) * log2(e): softmax computed in exp2 domain; folded into Q at QKV epilogue
#define QSCALE 0.18033688011112042f

typedef unsigned short u16;
typedef __attribute__((ext_vector_type(8))) short bf16x8;   // 8 bf16 = 4 VGPR
typedef __attribute__((ext_vector_type(4))) float f32x4;    // MFMA acc

__device__ __forceinline__ u16 f2bf(float f) {
    union { float f; unsigned u; } v; v.f = f;
    return (u16)((v.u + 0x7FFFu + ((v.u >> 16) & 1u)) >> 16);
}

// async global->LDS, 16B per lane. LDS dest must be wave-uniform base + lane*16.
__device__ __forceinline__ void async16(void* lds, const void* g) {
    __builtin_amdgcn_global_load_lds(
        (const __attribute__((address_space(1))) unsigned*)g,
        (__attribute__((address_space(3))) unsigned*)lds, 16, 0, 0);
}

// tanh-form GELU (max |err| vs exact erf-GELU ~3e-3; threshold headroom 4x)
__device__ __forceinline__ float gelu_f(float v) {
    float u = 0.7978845608028654f * (v + 0.044715f * v * v * v);
    float e = __expf(2.f * u);
    float th = 1.f - 2.f * __builtin_amdgcn_rcpf(e + 1.f);
    return 0.5f * v * (1.f + th);
}

// ---------------- LayerNorm -> bf16 out: one block per row of 1024 -------------
__global__ __launch_bounds__(256) void ln_bf16(const float* __restrict__ x,
                                               const float* __restrict__ g,
                                               const float* __restrict__ b,
                                               u16* __restrict__ out)
{
    int row = blockIdx.x;
    const float* xr = x + (size_t)row * TD;
    u16* outr = out + (size_t)row * TD;
    int t = threadIdx.x;
    float v[4];
    float s = 0.f, ss = 0.f;
#pragma unroll
    for (int i = 0; i < 4; i++) {
        v[i] = xr[t + 256 * i];
        s += v[i];
        ss += v[i] * v[i];
    }
#pragma unroll
    for (int o = 32; o > 0; o >>= 1) {
        s  += __shfl_down(s, o);
        ss += __shfl_down(ss, o);
    }
    __shared__ float sm[4], sm2[4];
    int wave = t >> 6, lane = t & 63;
    if (lane == 0) { sm[wave] = s; sm2[wave] = ss; }
    __syncthreads();
    s  = sm[0] + sm[1] + sm[2] + sm[3];
    ss = sm2[0] + sm2[1] + sm2[2] + sm2[3];
    float mu  = s * (1.f / TD);
    float var = ss * (1.f / TD) - mu * mu;
    float rstd = rsqrtf(var + 1e-5f);
#pragma unroll
    for (int i = 0; i < 4; i++) {
        int c = t + 256 * i;
        outr[c] = f2bf((v[i] - mu) * rstd * g[c] + b[c]);
    }
}

// --- prep: fused weight convert+transpose (blocks 0..3071) + LN1 (3072..7167) --
__global__ __launch_bounds__(256) void prep_kernel(
    const float* __restrict__ Wqkv, const float* __restrict__ Wo,
    const float* __restrict__ W1,   const float* __restrict__ W2,
    u16* __restrict__ wqkvT, u16* __restrict__ woT,
    u16* __restrict__ w1T,   u16* __restrict__ w2T,
    const float* __restrict__ x, const float* __restrict__ g1,
    const float* __restrict__ b1, u16* __restrict__ hbuf)
{
    int blk = blockIdx.x;
    int t = threadIdx.x;
    if (blk >= 3072) {               // ---- LN1 path ----
        int row = blk - 3072;
        const float* xr = x + (size_t)row * TD;
        u16* outr = hbuf + (size_t)row * TD;
        float v[4];
        float s = 0.f, ss = 0.f;
#pragma unroll
        for (int i = 0; i < 4; i++) {
            v[i] = xr[t + 256 * i];
            s += v[i];
            ss += v[i] * v[i];
        }
#pragma unroll
        for (int o = 32; o > 0; o >>= 1) {
            s  += __shfl_down(s, o);
            ss += __shfl_down(ss, o);
        }
        __shared__ float sm[4], sm2[4];
        int wave = t >> 6, lane = t & 63;
        if (lane == 0) { sm[wave] = s; sm2[wave] = ss; }
        __syncthreads();
        s  = sm[0] + sm[1] + sm[2] + sm[3];
        ss = sm2[0] + sm2[1] + sm2[2] + sm2[3];
        float mu  = s * (1.f / TD);
        float var = ss * (1.f / TD) - mu * mu;
        float rstd = rsqrtf(var + 1e-5f);
#pragma unroll
        for (int i = 0; i < 4; i++) {
            int c = t + 256 * i;
            outr[c] = f2bf((v[i] - mu) * rstd * g1[c] + b1[c]);
        }
        return;
    }
    // ---- weight transpose path ----
    const float* W; u16* Wt; int K, N, local, nx;
    if (blk < 768)       { W = Wqkv; Wt = wqkvT; K = TD;  N = 3 * TD; local = blk;        nx = 48; }
    else if (blk < 1024) { W = Wo;   Wt = woT;   K = TD;  N = TD;     local = blk - 768;  nx = 16; }
    else if (blk < 2048) { W = W1;   Wt = w1T;   K = TD;  N = FFD;    local = blk - 1024; nx = 64; }
    else                 { W = W2;   Wt = w2T;   K = FFD; N = TD;     local = blk - 2048; nx = 16; }
    int n0 = (local % nx) * 64, k0 = (local / nx) * 64;
    __shared__ u16 tile[64][65];
    int c = t & 63, rq = t >> 6;
#pragma unroll
    for (int i = 0; i < 16; i++) {
        int r = rq * 16 + i;
        tile[r][c] = f2bf(W[(size_t)(k0 + r) * N + n0 + c]);
    }
    __syncthreads();
#pragma unroll
    for (int i = 0; i < 16; i++) {
        int r = rq * 16 + i;
        Wt[(size_t)(n0 + r) * K + k0 + c] = tile[c][r];
    }
}

// ---------------- bf16 MFMA GEMM: 128xTN tile, BK k-slab, dbuf LDS -------------
// (legacy 2-barrier structure. Measured: TN128/BK32 best for K=1024 fully-
// resident grids (W1 55.1us, R18); QKV moved to BK32 (R21, twin geometry).
// Wo/W2 stay 64/64: 512-block grids are grid-capped, BK change is pure cost.)
#define EPI_QKV 0
#define EPI_F32RES 1
#define EPI_GELU 2

template<int EPI, int TN, int BK>
__global__ __launch_bounds__(256) void gemm_mfma(int M, int N, int K,
    const u16* __restrict__ A, const u16* __restrict__ Bt,
    const float* __restrict__ bias, const float* __restrict__ res,
    float* __restrict__ Cf, u16* __restrict__ Cb,
    u16* __restrict__ qb, u16* __restrict__ kb, u16* __restrict__ vb)
{
    constexpr int WN  = TN / 2;               // per-wave N extent (2 waves along N)
    constexpr int NJ  = WN / 16;              // B frags per wave
    constexpr int KH  = BK / 32;              // 32-elem k-halves per slab
    constexpr int CPR = BK / 8;               // 16B chunks per tile-row
    constexpr int ACH = (128 * CPR) / 256;    // A chunks per thread
    constexpr int BCH = (TN  * CPR) / 256;    // B chunks per thread
    constexpr int ASZ = 128 * BK * 2;         // bytes per A buffer
    constexpr int BSZ = TN  * BK * 2;
    __shared__ __align__(16) char smem[2 * (ASZ + BSZ)];

    int t = threadIdx.x;
    int lane = t & 63, w = t >> 6;
    int wm = w >> 1, wn = w & 1;              // 2x2 wave grid: wave = 64(M) x WN(N)
    int lr = lane & 15, lq = lane >> 4;
    int gx = gridDim.x;
    int lin = blockIdx.x + gx * blockIdx.y;
    int li = lin >> 3;
    int qy = li / gx;
    int ty = (lin & 7) * (gridDim.y >> 3) + qy;
    int tx = li - qy * gx;
    int m0 = ty * 128, n0 = tx * TN;
    int pg = (lq ^ (lr & (CPR - 1))) * 16;    // swizzled frag-read granule offset

    const u16* ap[ACH];
    const u16* bp[BCH];
#pragma unroll
    for (int i = 0; i < ACH; i++) {
        int c = t + 256 * i, r = c / CPR, s = c % CPR;
        int g = s ^ (r & (CPR - 1));
        ap[i] = A + (size_t)(m0 + r) * K + g * 8;
    }
#pragma unroll
    for (int i = 0; i < BCH; i++) {
        int c = t + 256 * i, r = c / CPR, s = c % CPR;
        int g = s ^ (r & (CPR - 1));
        bp[i] = Bt + (size_t)(n0 + r) * K + g * 8;
    }

    f32x4 acc[4][NJ];
#pragma unroll
    for (int i = 0; i < 4; i++)
#pragma unroll
        for (int j = 0; j < NJ; j++) acc[i][j] = (f32x4){0.f, 0.f, 0.f, 0.f};

#pragma unroll
    for (int i = 0; i < ACH; i++)
        async16(smem + (t + 256 * i) * 16, ap[i]);
#pragma unroll
    for (int i = 0; i < BCH; i++)
        async16(smem + 2 * ASZ + (t + 256 * i) * 16, bp[i]);

    int nk = K / BK;
    for (int kt = 0; kt < nk; kt++) {
        int cur = kt & 1;
        __syncthreads();
        if (kt + 1 < nk) {
            char* An = smem + (1 - cur) * ASZ;
            char* Bn = smem + 2 * ASZ + (1 - cur) * BSZ;
#pragma unroll
            for (int i = 0; i < ACH; i++) {
                ap[i] += BK;
                async16(An + (t + 256 * i) * 16, ap[i]);
            }
#pragma unroll
            for (int i = 0; i < BCH; i++) {
                bp[i] += BK;
                async16(Bn + (t + 256 * i) * 16, bp[i]);
            }
        }
        const char* Ac = smem + cur * ASZ;
        const char* Bc = smem + 2 * ASZ + cur * BSZ;
#pragma unroll
        for (int h = 0; h < KH; h++) {
            bf16x8 af[4], bfr[NJ];
#pragma unroll
            for (int i = 0; i < 4; i++)
                af[i] = *(const bf16x8*)(Ac + (wm * 64 + i * 16 + lr) * (2 * BK) + (pg ^ (h * 64)));
#pragma unroll
            for (int j = 0; j < NJ; j++)
                bfr[j] = *(const bf16x8*)(Bc + (wn * WN + j * 16 + lr) * (2 * BK) + (pg ^ (h * 64)));
#pragma unroll
            for (int i = 0; i < 4; i++)
#pragma unroll
                for (int j = 0; j < NJ; j++)
                    acc[i][j] = __builtin_amdgcn_mfma_f32_16x16x32_bf16(af[i], bfr[j], acc[i][j], 0, 0, 0);
        }
    }

#pragma unroll
    for (int i = 0; i < 4; i++) {
        int rowb = m0 + wm * 64 + i * 16 + lq * 4;
#pragma unroll
        for (int j = 0; j < NJ; j++) {
            int col = n0 + wn * WN + j * 16 + lr;
            float bs = bias[col];
            float vals[4];
#pragma unroll
            for (int r = 0; r < 4; r++) vals[r] = acc[i][j][r] + bs;
            if (EPI == EPI_F32RES) {
#pragma unroll
                for (int r = 0; r < 4; r++) {
                    int rr = rowb + r;
                    Cf[(size_t)rr * N + col] = vals[r] + res[(size_t)rr * N + col];
                }
            } else if (EPI == EPI_GELU) {
#pragma unroll
                for (int r = 0; r < 4; r++)
                    Cb[(size_t)(rowb + r) * N + col] = f2bf(gelu_f(vals[r]));
            } else { // QKV scatter: Q/K [bh][seq][64] (Q pre-scaled), V [bh][64][seq]
                int comp = col >> 10, cw = col & 1023;
                int h = cw >> 6, d = cw & 63;
                int bb0 = rowb >> 11, ts = rowb & 2047;   // rowb%4==0: no batch crossing
                int bh = bb0 * NH + h;
                if (comp == 0) {
#pragma unroll
                    for (int r = 0; r < 4; r++)
                        qb[((size_t)bh * SEQ + ts + r) * HDIM + d] = f2bf(vals[r] * QSCALE);
                } else if (comp == 1) {
#pragma unroll
                    for (int r = 0; r < 4; r++)
                        kb[((size_t)bh * SEQ + ts + r) * HDIM + d] = f2bf(vals[r]);
                } else {
                    ushort4 pk;
                    pk.x = f2bf(vals[0]); pk.y = f2bf(vals[1]);
                    pk.z = f2bf(vals[2]); pk.w = f2bf(vals[3]);
                    *(ushort4*)&vb[((size_t)bh * HDIM + d) * SEQ + ts] = pk;
                }
            }
        }
    }
}

// -------- W1 GEMM v2: 256x256 tile, BK=64, 8 waves, counted-vmcnt pipeline -----
// Measured R19/R20 timing-run arithmetic: ~52us (vs 55.1 legacy). R20's 75us
// profile reading is inconsistent with both timing totals -> replay artifact.
__global__ __launch_bounds__(512) void gemm256_gelu(
    const u16* __restrict__ A, const u16* __restrict__ Bt,
    const float* __restrict__ bias, u16* __restrict__ Cb)
{
    constexpr int BK  = 64;
    constexpr int ASZ = 256 * BK * 2;          // 32KB per A buffer
    constexpr int BSZ = 256 * BK * 2;          // 32KB per B buffer
    __shared__ __align__(16) char smem[2 * (ASZ + BSZ)];   // 128KB

    int t = threadIdx.x;
    int lane = t & 63, w = t >> 6;
    int wm = w >> 2, wn = w & 3;               // 2M x 4N wave grid
    int lr = lane & 15, lq = lane >> 4;
    int gx = gridDim.x;
    int lin = blockIdx.x + gx * blockIdx.y;
    int li = lin >> 3;
    int qy = li / gx;
    int ty = (lin & 7) * (gridDim.y >> 3) + qy;
    int tx = li - qy * gx;
    int m0 = ty * 256, n0 = tx * 256;
    int pg = (lq ^ (lr & 7)) * 16;

    const u16* ap[4];
    const u16* bp[4];
#pragma unroll
    for (int i = 0; i < 4; i++) {
        int c = t + 512 * i, r = c >> 3, s = c & 7;
        int g = s ^ (r & 7);
        ap[i] = A  + (size_t)(m0 + r) * TD + g * 8;
        bp[i] = Bt + (size_t)(n0 + r) * TD + g * 8;
    }

    f32x4 acc[8][4];
#pragma unroll
    for (int i = 0; i < 8; i++)
#pragma unroll
        for (int j = 0; j < 4; j++) acc[i][j] = (f32x4){0.f, 0.f, 0.f, 0.f};

#pragma unroll
    for (int s = 0; s < 2; s++) {
        char* Ab = smem + s * ASZ;
        char* Bb = smem + 2 * ASZ + s * BSZ;
#pragma unroll
        for (int i = 0; i < 4; i++) {
            async16(Ab + (t + 512 * i) * 16, ap[i]);
            ap[i] += BK;
        }
#pragma unroll
        for (int i = 0; i < 4; i++) {
            async16(Bb + (t + 512 * i) * 16, bp[i]);
            bp[i] += BK;
        }
    }

    constexpr int nk = TD / BK;                // 16 slabs
    for (int kt = 0; kt < nk; kt++) {
        int cur = kt & 1;
        if (kt + 1 < nk) asm volatile("s_waitcnt vmcnt(8)" ::: "memory");
        else             asm volatile("s_waitcnt vmcnt(0)" ::: "memory");
        __builtin_amdgcn_sched_barrier(0);
        __builtin_amdgcn_s_barrier();          // slab kt visible to all waves
        __builtin_amdgcn_sched_barrier(0);
        const char* Ac = smem + cur * ASZ;
        const char* Bc = smem + 2 * ASZ + cur * BSZ;
        __builtin_amdgcn_s_setprio(1);
#pragma unroll
        for (int h = 0; h < 2; h++) {
            bf16x8 af[8], bfr[4];
#pragma unroll
            for (int i = 0; i < 8; i++)
                af[i] = *(const bf16x8*)(Ac + (wm * 128 + i * 16 + lr) * 128 + (pg ^ (h * 64)));
#pragma unroll
            for (int j = 0; j < 4; j++)
                bfr[j] = *(const bf16x8*)(Bc + (wn * 64 + j * 16 + lr) * 128 + (pg ^ (h * 64)));
#pragma unroll
            for (int i = 0; i < 8; i++)
#pragma unroll
                for (int j = 0; j < 4; j++)
                    acc[i][j] = __builtin_amdgcn_mfma_f32_16x16x32_bf16(af[i], bfr[j], acc[i][j], 0, 0, 0);
        }
        __builtin_amdgcn_s_setprio(0);
        asm volatile("s_waitcnt lgkmcnt(0)" ::: "memory");
        __builtin_amdgcn_sched_barrier(0);
        __builtin_amdgcn_s_barrier();
        __builtin_amdgcn_sched_barrier(0);
        if (kt + 2 < nk) {                     // stage slab kt+2 into freed buffer
            char* An = smem + cur * ASZ;
            char* Bn = smem + 2 * ASZ + cur * BSZ;
#pragma unroll
            for (int i = 0; i < 4; i++) {
                async16(An + (t + 512 * i) * 16, ap[i]);
                ap[i] += BK;
            }
#pragma unroll
            for (int i = 0; i < 4; i++) {
                async16(Bn + (t + 512 * i) * 16, bp[i]);
                bp[i] += BK;
            }
        }
    }

#pragma unroll
    for (int i = 0; i < 8; i++) {
        int rowb = m0 + wm * 128 + i * 16 + lq * 4;
#pragma unroll
        for (int j = 0; j < 4; j++) {
            int col = n0 + wn * 64 + j * 16 + lr;
            float bs = bias[col];
#pragma unroll
            for (int r = 0; r < 4; r++)
                Cb[(size_t)(rowb + r) * FFD + col] = f2bf(gelu_f(acc[i][j][r] + bs));
        }
    }
}

// ---------------- flash attention v5: v4 + defer-max (T13) + max-tree ----------
// Measured R20: passed, attn left top-5, total -2.6us. Kept.
__global__ __launch_bounds__(256, 4) void attn_mfma(const u16* __restrict__ qb,
                                                    const u16* __restrict__ kb,
                                                    const u16* __restrict__ vb,
                                                    u16* __restrict__ ctx)
{
    __shared__ __align__(16) char smem[40960];
    char* QP = smem;                        // 8KB Q tile / P buffer (wave-private rows)
    int lin = blockIdx.x + 32 * blockIdx.y;
    int xcd = lin & 7, idx = lin >> 3;      // idx 0..127 within XCD
    int u = idx & 31, v = idx >> 5;         // u: CU slot, v: round
    int bh = xcd + 8 * v;
    int qt = (v & 1) ? u : 31 - u;
    int bb = bh >> 4, h = bh & 15;
    int t = threadIdx.x, lane = t & 63, w = t >> 6;
    int lr = lane & 15, lq = lane >> 4;
    int sw = (lr & 7) * 16;                 // read-side swizzle
    int cA = (lq * 16) ^ sw;                // chunk lq   (k-half 0)
    int cB = (64 | (lq * 16)) ^ sw;         // chunk 4+lq (k-half 1)
    int c0 = t,        r0 = c0 >> 3, g0 = (c0 & 7) ^ (r0 & 7);
    int c1 = t + 256,  r1 = c1 >> 3, g1 = (c1 & 7) ^ (r1 & 7);
    size_t off0  = (size_t)r0 * 128  + g0 * 16;   // Q/K tiles: 128B per row
    size_t off1  = (size_t)r1 * 128  + g1 * 16;
    size_t voff0 = (size_t)r0 * 4096 + g0 * 16;   // V: row=d, global stride 4096B
    size_t voff1 = (size_t)r1 * 4096 + g1 * 16;

    const char* qg_base = (const char*)qb + (size_t)bh * SEQ * 128;
    const char* kg_base = (const char*)kb + (size_t)bh * SEQ * 128;
    const char* vg_base = (const char*)vb + (size_t)bh * 64 * 4096;

    const char* qg = qg_base + (size_t)qt * 8192;
    async16(QP + c0 * 16, qg + off0);
    async16(QP + c1 * 16, qg + off1);
    async16(smem + 8192 + c0 * 16, kg_base + off0);
    async16(smem + 8192 + c1 * 16, kg_base + off1);
    async16(smem + 24576 + c0 * 16, vg_base + voff0);
    async16(smem + 24576 + c1 * 16, vg_base + voff1);

    float mold = -INFINITY, lsum = 0.f;
    f32x4 o[4];
#pragma unroll
    for (int dj = 0; dj < 4; dj++) o[dj] = (f32x4){0.f, 0.f, 0.f, 0.f};
    bf16x8 bq0, bq1;

    for (int kt = 0; kt <= qt; ++kt) {
        int cur = kt & 1;
        __syncthreads();                // tile kt ready; other buf free
        if (kt < qt) {                  // prefetch kt+1 (drained at next barrier)
            const char* kgn = kg_base + (size_t)(kt + 1) * 8192;
            const char* vgn = vg_base + (size_t)(kt + 1) * 128;
            char* Kn = smem + 8192  + (1 - cur) * 8192;
            char* Vn = smem + 24576 + (1 - cur) * 8192;
            async16(Kn + c0 * 16, kgn + off0);
            async16(Kn + c1 * 16, kgn + off1);
            async16(Vn + c0 * 16, vgn + voff0);
            async16(Vn + c1 * 16, vgn + voff1);
        }
        if (kt == 0) {                  // Q frags -> regs (QP then reused as P)
            const char* qr = QP + (w * 16 + lr) * 128;
            bq0 = *(const bf16x8*)(qr + cA);
            bq1 = *(const bf16x8*)(qr + cB);
        }
        const char* Kc = smem + 8192  + cur * 8192;
        const char* Vc = smem + 24576 + cur * 8192;

        // S^T = K Q^T : lane holds keys j*16+lq*4+r (rows), q = w*16+lr (col)
        float sv[4][4];
        bool diag = (kt == qt);
        __builtin_amdgcn_s_setprio(1);
#pragma unroll
        for (int j = 0; j < 4; ++j) {
            const char* kr = Kc + (j * 16 + lr) * 128;
            bf16x8 ak0 = *(const bf16x8*)(kr + cA);
            bf16x8 ak1 = *(const bf16x8*)(kr + cB);
            f32x4 z = (f32x4){0.f, 0.f, 0.f, 0.f};
            z = __builtin_amdgcn_mfma_f32_16x16x32_bf16(ak0, bq0, z, 0, 0, 0);
            z = __builtin_amdgcn_mfma_f32_16x16x32_bf16(ak1, bq1, z, 0, 0, 0);
#pragma unroll
            for (int r = 0; r < 4; r++) {
                float xv = z[r];
                if (diag && (j * 16 + lq * 4 + r > w * 16 + lr)) xv = -INFINITY;
                sv[j][r] = xv;
            }
        }
        __builtin_amdgcn_s_setprio(0);
        // tile max: 4-deep pairwise tree (was 16-deep serial chain)
        float m0a = fmaxf(fmaxf(sv[0][0], sv[0][1]), fmaxf(sv[0][2], sv[0][3]));
        float m1a = fmaxf(fmaxf(sv[1][0], sv[1][1]), fmaxf(sv[1][2], sv[1][3]));
        float m2a = fmaxf(fmaxf(sv[2][0], sv[2][1]), fmaxf(sv[2][2], sv[2][3]));
        float m3a = fmaxf(fmaxf(sv[3][0], sv[3][1]), fmaxf(sv[3][2], sv[3][3]));
        float pmax = fmaxf(fmaxf(m0a, m1a), fmaxf(m2a, m3a));
        pmax = fmaxf(pmax, __shfl_xor(pmax, 16));
        pmax = fmaxf(pmax, __shfl_xor(pmax, 32));
        // defer-max: rescale only when running max grows by > 8 (wave-uniform)
        if (!__all(pmax - mold <= 8.f)) {
            float mnew = fmaxf(mold, pmax);
            float alpha = exp2f(mold - mnew);
            lsum *= alpha;
#pragma unroll
            for (int dj = 0; dj < 4; dj++)
#pragma unroll
                for (int r = 0; r < 4; r++) o[dj][r] *= alpha;
            mold = mnew;
        }
        float rs = 0.f;
        unsigned pk[4][2];
#pragma unroll
        for (int j = 0; j < 4; j++)
#pragma unroll
            for (int hh = 0; hh < 2; hh++) {
                float p0 = exp2f(sv[j][2 * hh]     - mold);
                float p1 = exp2f(sv[j][2 * hh + 1] - mold);
                rs += p0 + p1;
                union { float f; unsigned u; } a0, a1;
                a0.f = p0; a1.f = p1;
                // truncation-pack: D = {hi16(p1), hi16(p0)} in ONE v_perm_b32
                pk[j][hh] = __builtin_amdgcn_perm(a1.u, a0.u, 0x07060302u);
            }
        rs += __shfl_xor(rs, 16);
        rs += __shfl_xor(rs, 32);
        lsum += rs;

        // P^T -> LDS (wave-private rows; no barrier): row q=w*16+lr, b64 writes
        {
            char* pw = QP + (w * 16 + lr) * 128 + (lq & 1) * 8;
#pragma unroll
            for (int j = 0; j < 4; j++) {
                int pos = ((j * 2 + (lq >> 1)) * 16) ^ sw;
                uint2 u2; u2.x = pk[j][0]; u2.y = pk[j][1];
                *(uint2*)(pw + pos) = u2;
            }
        }
        asm volatile("s_waitcnt lgkmcnt(0)" ::: "memory");
        const char* pr = QP + (w * 16 + lr) * 128;
        bf16x8 bp0 = *(const bf16x8*)(pr + cA);
        bf16x8 bp1 = *(const bf16x8*)(pr + cB);
        // O^T += V^T P^T : rows d, cols q
        __builtin_amdgcn_s_setprio(1);
#pragma unroll
        for (int dj = 0; dj < 4; ++dj) {
            const char* vr = Vc + (dj * 16 + lr) * 128;
            bf16x8 av0 = *(const bf16x8*)(vr + cA);
            bf16x8 av1 = *(const bf16x8*)(vr + cB);
            o[dj] = __builtin_amdgcn_mfma_f32_16x16x32_bf16(av0, bp0, o[dj], 0, 0, 0);
            o[dj] = __builtin_amdgcn_mfma_f32_16x16x32_bf16(av1, bp1, o[dj], 0, 0, 0);
        }
        __builtin_amdgcn_s_setprio(0);
    }

    float inv = 1.f / lsum;
    int tok = qt * 64 + w * 16 + lr;
    u16* cp = ctx + ((size_t)(bb * SEQ) + tok) * TD + h * HDIM + lq * 4;
#pragma unroll
    for (int dj = 0; dj < 4; dj++) {
        ushort4 s4;
        s4.x = f2bf(o[dj][0] * inv); s4.y = f2bf(o[dj][1] * inv);
        s4.z = f2bf(o[dj][2] * inv); s4.w = f2bf(o[dj][3] * inv);
        *(ushort4*)(cp + dj * 16) = s4;
    }
}

extern "C" void kernel_launch(void* const* d_in, const int* in_sizes, int n_in,
                              void* d_out, int out_size, void* d_ws, size_t ws_size,
                              hipStream_t stream)
{
    const float* x    = (const float*)d_in[0];
    const float* g1   = (const float*)d_in[1];
    const float* b1   = (const float*)d_in[2];
    const float* Wqkv = (const float*)d_in[3];
    const float* bqkv = (const float*)d_in[4];
    const float* Wo   = (const float*)d_in[5];
    const float* bo   = (const float*)d_in[6];
    const float* g2   = (const float*)d_in[7];
    const float* b2   = (const float*)d_in[8];
    const float* W1   = (const float*)d_in[9];
    const float* b1f  = (const float*)d_in[10];
    const float* W2   = (const float*)d_in[11];
    const float* b2f  = (const float*)d_in[12];
    float* out = (float*)d_out;

    char* ws = (char*)d_ws;
    const size_t MB = 1ull << 20;
    u16* wqkvT = (u16*)(ws + 0 * MB);    // 6 MB  [3072][1024]
    u16* woT   = (u16*)(ws + 6 * MB);    // 2 MB  [1024][1024]
    u16* w1T   = (u16*)(ws + 8 * MB);    // 8 MB  [4096][1024]
    u16* w2T   = (u16*)(ws + 16 * MB);   // 8 MB  [1024][4096]
    u16* qbuf  = (u16*)(ws + 24 * MB);   // 8 MB  [32][2048][64] (pre-scaled)
    u16* kbuf  = (u16*)(ws + 32 * MB);   // 8 MB
    u16* vbuf  = (u16*)(ws + 40 * MB);   // 8 MB  [32][64][2048]
    u16* hbuf  = (u16*)(ws + 48 * MB);   // 8 MB  h then hh
    u16* ctx   = (u16*)(ws + 56 * MB);   // 8 MB
    float* x2  = (float*)(ws + 64 * MB); // 16 MB
    u16* ff1   = (u16*)(ws + 80 * MB);   // 32 MB  -> 112 MB total

    // fused: weight transposes + LN1 (independent work, one dispatch)
    prep_kernel<<<3072 + NROWS, 256, 0, stream>>>(
        Wqkv, Wo, W1, W2, wqkvT, woT, w1T, w2T, x, g1, b1, hbuf);

    // QKV: BK=32 (32KB LDS -> 768 blocks fully resident; twin of W1's measured
    // 64->55.1us gain, also ran in R6 assembly without regression)
    gemm_mfma<EPI_QKV, 128, 32><<<dim3(3 * TD / 128, NROWS / 128), 256, 0, stream>>>(
        NROWS, 3 * TD, TD, hbuf, wqkvT, bqkv, nullptr, nullptr, nullptr, qbuf, kbuf, vbuf);
    attn_mfma<<<dim3(32, NB * NH), 256, 0, stream>>>(qbuf, kbuf, vbuf, ctx);
    gemm_mfma<EPI_F32RES, 64, 64><<<dim3(TD / 64, NROWS / 128), 256, 0, stream>>>(
        NROWS, TD, TD, ctx, woT, bo, x, x2, nullptr, nullptr, nullptr, nullptr);
    ln_bf16<<<NROWS, 256, 0, stream>>>(x2, g2, b2, hbuf);
    gemm256_gelu<<<dim3(FFD / 256, NROWS / 256), 512, 0, stream>>>(hbuf, w1T, b1f, ff1);
    gemm_mfma<EPI_F32RES, 64, 64><<<dim3(TD / 64, NROWS / 128), 256, 0, stream>>>(
        NROWS, TD, FFD, ff1, w2T, b2f, x2, out, nullptr, nullptr, nullptr, nullptr);
}